// Round 18
// baseline (1820.196 us; speedup 1.0000x reference)
//
#include <hip/hip_runtime.h>
#include <hip/hip_bf16.h>
#include <math.h>

// Problem constants
#define NN 10000      // nodes
#define NE 50000      // edges
#define NBLK 6
#define MAXD 256      // degree clamp for counting sort
// feature split: C0=128 scalars, C1=64 l1-vectors (3 comps), C2=32 l2-vectors (5 comps)
// planar layout inside a node-feature buffer of NN*480 elems:
//   S  at [0, NN*128)                 row-major N x 128
//   V1 plane m at NN*128 + m*NN*64    row-major N x 64, m=0..2
//   V2 plane m at NN*320 + m*NN*32    row-major N x 32, m=0..4
#define V1_OFF (NN*128)
#define V2_OFF (NN*320)

typedef __hip_bfloat16 bf16;
typedef __attribute__((ext_vector_type(8))) short short8;
typedef __attribute__((ext_vector_type(4))) short short4v;
typedef __attribute__((ext_vector_type(4))) float f32x4;

__device__ __forceinline__ float ldw(const float* p){ return *p; }
__device__ __forceinline__ float ldw(const bf16* p){ return __bfloat162float(*p); }
__device__ __forceinline__ void stw(float* p, float v){ *p = v; }
__device__ __forceinline__ void stw(bf16* p, float v){ *p = __float2bfloat16(v); }
__device__ __forceinline__ float b2f(short u){
  unsigned int x = ((unsigned int)(unsigned short)u) << 16;
  return __builtin_bit_cast(float, x);
}
__device__ __forceinline__ short f2b(float v){
  return __builtin_bit_cast(short, (unsigned short)(__builtin_bit_cast(unsigned int, v) >> 16 ));
}

// ---------------------------------------------------------------- MFMA GEMM
// C[M x Nn] = A[M x K] @ B; A bf16 row-major (lda); B PRE-TRANSPOSED bf16
// Bt[Nn x K] row-major (ld=K). f32 accumulate. K mult of 32.
// epi: 0=store, 1=silu, 2=accumulate into C, 3=sigmoid
template<typename OutT>
__global__ __launch_bounds__(256)
void mgemm_kernel(const bf16* __restrict__ A, const bf16* __restrict__ Bt,
                  OutT* __restrict__ C, int M, int Nn, int K,
                  int lda, int ldc, int epi)
{
  __shared__ __align__(16) unsigned short Ash[64][40];
  __shared__ __align__(16) unsigned short Bsh[64][40];
  int tid  = threadIdx.x;
  int wid  = tid >> 6, lane = tid & 63;
  int wr   = wid >> 1, wc = wid & 1;
  int rowBase = blockIdx.x * 64, colBase = blockIdx.y * 64;
  int fr = lane & 15;
  int fk = (lane >> 4) * 8;
  f32x4 acc[2][2] = {};
  int am = tid >> 2, ako = (tid & 3) * 8;

  for (int k0 = 0; k0 < K; k0 += 32) {
    {
      int gm = rowBase + am;
      short8 v = {0,0,0,0,0,0,0,0};
      if (gm < M) v = *reinterpret_cast<const short8*>(A + (long)gm * lda + k0 + ako);
      *reinterpret_cast<short8*>(&Ash[am][ako]) = v;
    }
    {
      int gn = colBase + am;
      short8 v = {0,0,0,0,0,0,0,0};
      if (gn < Nn) v = *reinterpret_cast<const short8*>(Bt + (long)gn * K + k0 + ako);
      *reinterpret_cast<short8*>(&Bsh[am][ako]) = v;
    }
    __syncthreads();
    short8 a0 = *reinterpret_cast<const short8*>(&Ash[wr*32 +      fr][fk]);
    short8 a1 = *reinterpret_cast<const short8*>(&Ash[wr*32 + 16 + fr][fk]);
    short8 b0 = *reinterpret_cast<const short8*>(&Bsh[wc*32 +      fr][fk]);
    short8 b1 = *reinterpret_cast<const short8*>(&Bsh[wc*32 + 16 + fr][fk]);
    acc[0][0] = __builtin_amdgcn_mfma_f32_16x16x32_bf16(a0, b0, acc[0][0], 0, 0, 0);
    acc[0][1] = __builtin_amdgcn_mfma_f32_16x16x32_bf16(a0, b1, acc[0][1], 0, 0, 0);
    acc[1][0] = __builtin_amdgcn_mfma_f32_16x16x32_bf16(a1, b0, acc[1][0], 0, 0, 0);
    acc[1][1] = __builtin_amdgcn_mfma_f32_16x16x32_bf16(a1, b1, acc[1][1], 0, 0, 0);
    __syncthreads();
  }
  int erow = (lane >> 4) * 4, ecol = lane & 15;
  #pragma unroll
  for (int tm = 0; tm < 2; tm++) {
    #pragma unroll
    for (int tn = 0; tn < 2; tn++) {
      #pragma unroll
      for (int r = 0; r < 4; r++) {
        int gm = rowBase + wr*32 + tm*16 + erow + r;
        int gn = colBase + wc*32 + tn*16 + ecol;
        if (gm < M && gn < Nn) {
          float v = acc[tm][tn][r];
          long off = (long)gm * ldc + gn;
          if (epi == 1)      v = v / (1.f + expf(-v));
          else if (epi == 2) v = v + ldw(&C[off]);
          else if (epi == 3) v = 1.f / (1.f + expf(-v));
          stw(&C[off], v);
        }
      }
    }
  }
}

// ---------------------------------------------------------------- grouped GEMM
// up to 4 independent segments in one dispatch (flattened tight grid)
// epi==5: cols<128 -> C (bf16, ld 128); 128..191 -> aux1 slot5 (xrec);
//         192..223 -> aux2 slot5 (xrec2)
struct GSeg {
  const bf16* A; const bf16* Bt; char* C;
  char* aux1; char* aux2;
  int M, N, K, lda, ldc, epi, outBf16, blk0, nbx;
};

__global__ __launch_bounds__(256)
void gseg_kernel(GSeg s0, GSeg s1, GSeg s2, GSeg s3, int nseg)
{
  GSeg s = s0;
  int b = blockIdx.x;
  if (nseg > 1 && b >= s1.blk0) s = s1;
  if (nseg > 2 && b >= s2.blk0) s = s2;
  if (nseg > 3 && b >= s3.blk0) s = s3;
  int rel = b - s.blk0;
  int bx = rel % s.nbx, by = rel / s.nbx;

  __shared__ __align__(16) unsigned short Ash[64][40];
  __shared__ __align__(16) unsigned short Bsh[64][40];
  int tid  = threadIdx.x;
  int wid  = tid >> 6, lane = tid & 63;
  int wr   = wid >> 1, wc = wid & 1;
  int rowBase = bx * 64, colBase = by * 64;
  int fr = lane & 15;
  int fk = (lane >> 4) * 8;
  f32x4 acc[2][2] = {};
  int am = tid >> 2, ako = (tid & 3) * 8;

  for (int k0 = 0; k0 < s.K; k0 += 32) {
    {
      int gm = rowBase + am;
      short8 v = {0,0,0,0,0,0,0,0};
      if (gm < s.M) v = *reinterpret_cast<const short8*>(s.A + (long)gm * s.lda + k0 + ako);
      *reinterpret_cast<short8*>(&Ash[am][ako]) = v;
    }
    {
      int gn = colBase + am;
      short8 v = {0,0,0,0,0,0,0,0};
      if (gn < s.N) v = *reinterpret_cast<const short8*>(s.Bt + (long)gn * s.K + k0 + ako);
      *reinterpret_cast<short8*>(&Bsh[am][ako]) = v;
    }
    __syncthreads();
    short8 a0 = *reinterpret_cast<const short8*>(&Ash[wr*32 +      fr][fk]);
    short8 a1 = *reinterpret_cast<const short8*>(&Ash[wr*32 + 16 + fr][fk]);
    short8 b0 = *reinterpret_cast<const short8*>(&Bsh[wc*32 +      fr][fk]);
    short8 b1 = *reinterpret_cast<const short8*>(&Bsh[wc*32 + 16 + fr][fk]);
    acc[0][0] = __builtin_amdgcn_mfma_f32_16x16x32_bf16(a0, b0, acc[0][0], 0, 0, 0);
    acc[0][1] = __builtin_amdgcn_mfma_f32_16x16x32_bf16(a0, b1, acc[0][1], 0, 0, 0);
    acc[1][0] = __builtin_amdgcn_mfma_f32_16x16x32_bf16(a1, b0, acc[1][0], 0, 0, 0);
    acc[1][1] = __builtin_amdgcn_mfma_f32_16x16x32_bf16(a1, b1, acc[1][1], 0, 0, 0);
    __syncthreads();
  }
  int erow = (lane >> 4) * 4, ecol = lane & 15;
  #pragma unroll
  for (int tm = 0; tm < 2; tm++) {
    #pragma unroll
    for (int tn = 0; tn < 2; tn++) {
      #pragma unroll
      for (int r = 0; r < 4; r++) {
        int gm = rowBase + wr*32 + tm*16 + erow + r;
        int gn = colBase + wc*32 + tn*16 + ecol;
        if (gm < s.M && gn < s.N) {
          float v = acc[tm][tn][r];
          if (s.epi == 5) {
            if (gn < 128)
              stw((bf16*)s.C + (long)gm * 128 + gn, v);
            else if (gn < 192)
              ((bf16*)s.aux1)[(size_t)gm*512 + (gn-128)*8 + 5] = __float2bfloat16(v);
            else
              ((bf16*)s.aux2)[(size_t)gm*256 + (gn-192)*8 + 5] = __float2bfloat16(v);
          } else {
            long off = (long)gm * s.ldc + gn;
            if (s.epi == 1)      v = v / (1.f + expf(-v));
            else if (s.epi == 2) v = v + (s.outBf16 ? ldw((const bf16*)s.C + off)
                                                   : ldw((const float*)s.C + off));
            else if (s.epi == 3) v = 1.f / (1.f + expf(-v));
            if (s.outBf16) stw((bf16*)s.C + off, v);
            else           stw((float*)s.C + off, v);
          }
        }
      }
    }
  }
}

// ---------------------------------------------------------------- transpose+cvt
__global__ void transp_kernel(const float* __restrict__ src, bf16* __restrict__ dst,
                              int R, int C, long sSrc, long sDst)
{
  src += (long)blockIdx.z * sSrc;
  dst += (long)blockIdx.z * sDst;
  int idx = blockIdx.x * 256 + threadIdx.x;
  if (idx < R * C) {
    int r = idx / C, c = idx - r * C;
    dst[(long)c * R + r] = __float2bfloat16(src[idx]);
  }
}

// R3 transpose with attn-packed column permutation:
// new col layout: [t*8+j] j=0..7 -> old cols {t,64+t,128+t,192+t,320+t,384+t,448+t,512+t}
//                 [512+t32*4+j] j=0..3 -> old cols {256+t32,288+t32,576+t32,608+t32}
__global__ void transp_r3_kernel(const float* __restrict__ src, bf16* __restrict__ dst)
{
  int idx = blockIdx.x * 256 + threadIdx.x;     // over NBLK*640*64
  if (idx >= NBLK * 640 * 64) return;
  int blk  = idx / (640 * 64);
  int rem  = idx - blk * 640 * 64;
  int newc = rem >> 6;          // dst row (0..639)
  int k    = rem & 63;          // dst col (K)
  int oldc;
  if (newc < 512) {
    int t = newc >> 3, j = newc & 7;
    const int base[8] = {0, 64, 128, 192, 320, 384, 448, 512};
    oldc = base[j] + t;
  } else {
    int q = newc - 512;
    int t32 = q >> 2, j = q & 3;
    const int base2[4] = {256, 288, 576, 608};
    oldc = base2[j] + t32;
  }
  dst[idx] = __float2bfloat16(src[(size_t)blk * 64 * 640 + (size_t)k * 640 + oldc]);
}

// ---------------------------------------------------------------- small kernels
__global__ void gather_atom_kernel(const int* __restrict__ z, const float* __restrict__ tab,
                                   float* __restrict__ s_atom, bf16* __restrict__ s_atom_bf)
{
  int idx = blockIdx.x * 256 + threadIdx.x;
  if (idx < NN * 128) {
    int n = idx >> 7, c = idx & 127;
    float v = tab[z[n] * 128 + c];
    s_atom[idx] = v;
    s_atom_bf[idx] = __float2bfloat16(v);
  }
}

__global__ void hist_kernel(const int* __restrict__ dst, int* __restrict__ counts)
{
  int e = blockIdx.x * 256 + threadIdx.x;
  if (e < NE) atomicAdd(&counts[dst[e]], 1);
}

__global__ __launch_bounds__(1024)
void scan_kernel(const int* __restrict__ counts, int* __restrict__ indptr,
                 int* __restrict__ nextp)
{
  __shared__ int totals[1024];
  const int PER = (NN + 1023) / 1024;   // 10
  int tid = threadIdx.x;
  int base = tid * PER;
  int local[PER];
  int s = 0;
  #pragma unroll
  for (int i = 0; i < PER; i++) {
    int idx = base + i;
    int c = (idx < NN) ? counts[idx] : 0;
    local[i] = s; s += c;
  }
  totals[tid] = s;
  __syncthreads();
  for (int off = 1; off < 1024; off <<= 1) {
    int v = (tid >= off) ? totals[tid - off] : 0;
    __syncthreads();
    totals[tid] += v;
    __syncthreads();
  }
  int prefix = (tid > 0) ? totals[tid - 1] : 0;
  #pragma unroll
  for (int i = 0; i < PER; i++) {
    int idx = base + i;
    if (idx < NN) { indptr[idx] = prefix + local[i]; nextp[idx] = prefix + local[i]; }
  }
  if (tid == 1023) indptr[NN] = totals[1023];
}

__global__ void scatter_kernel(const int* __restrict__ dst, int* __restrict__ nextp,
                               int* __restrict__ order)
{
  int e = blockIdx.x * 256 + threadIdx.x;
  if (e < NE) {
    int p = atomicAdd(&nextp[dst[e]], 1);
    order[p] = e;
  }
}

// ---- degree-descending node order (counting sort; output-order independent)
__global__ void dhist_kernel(const int* __restrict__ indptr, int* __restrict__ bins)
{
  int n = blockIdx.x * 256 + threadIdx.x;
  if (n < NN) {
    int d = indptr[n+1] - indptr[n]; if (d > MAXD-1) d = MAXD-1;
    atomicAdd(&bins[MAXD-1-d], 1);
  }
}
__global__ __launch_bounds__(256)
void dscan_kernel(const int* __restrict__ bins, int* __restrict__ boff)
{
  __shared__ int tmp[MAXD];
  int t = threadIdx.x;
  tmp[t] = bins[t];
  __syncthreads();
  for (int off = 1; off < MAXD; off <<= 1) {
    int v = (t >= off) ? tmp[t-off] : 0;
    __syncthreads();
    tmp[t] += v;
    __syncthreads();
  }
  boff[t] = tmp[t] - bins[t];
}
__global__ void dplace_kernel(const int* __restrict__ indptr, int* __restrict__ boff,
                              int* __restrict__ norder)
{
  int n = blockIdx.x * 256 + threadIdx.x;
  if (n < NN) {
    int d = indptr[n+1] - indptr[n]; if (d > MAXD-1) d = MAXD-1;
    int pos = atomicAdd(&boff[MAXD-1-d], 1);
    norder[pos] = n;
  }
}

// edge geometry, stored in CSR-permuted order (position idx = sorted-by-dst)
// y12: packed [y1[3] | y2[5]] per edge for attn vector loads
__global__ __launch_bounds__(128)
void edge_perm_kernel(const float* __restrict__ pos, const int* __restrict__ esrc,
                      const int* __restrict__ edst, const int* __restrict__ order,
                      int* __restrict__ srcp, bf16* __restrict__ rbf,
                      float* __restrict__ y1, float* __restrict__ y2,
                      float* __restrict__ y12)
{
  int idx = blockIdx.x, t = threadIdx.x;
  int e = order[idx];
  int s = esrc[e], d = edst[e];
  float vx = pos[d*3+0] - pos[s*3+0];
  float vy = pos[d*3+1] - pos[s*3+1];
  float vz = pos[d*3+2] - pos[s*3+2];
  float r = sqrtf(vx*vx + vy*vy + vz*vz + 1e-12f);
  float mu = t * (5.0f / 127.0f);
  const float inv_sig = 128.0f / 5.0f;
  float zq = (r - mu) * inv_sig;
  rbf[(long)idx * 128 + t] = __float2bfloat16(expf(-0.5f * zq * zq));
  if (t == 0) {
    srcp[idx] = s;
    float inv = 1.f / r;
    float ux = vx*inv, uy = vy*inv, uz = vz*inv;
    const float s3  = 1.7320508075688772f;   // sqrt(3)
    const float s15 = 3.872983346207417f;    // sqrt(15)
    float a0 = s3*ux, a1 = s3*uy, a2 = s3*uz;
    float b0 = s15*ux*uy;
    float b1 = s15*uy*uz;
    float b2 = 1.118033988749895f * (3.f*uz*uz - 1.f);   // sqrt(1.25)
    float b3 = s15*ux*uz;
    float b4 = 1.9364916731037085f * (ux*ux - uy*uy);    // sqrt(3.75)
    y1[idx*3+0] = a0; y1[idx*3+1] = a1; y1[idx*3+2] = a2;
    y2[idx*5+0] = b0; y2[idx*5+1] = b1; y2[idx*5+2] = b2;
    y2[idx*5+3] = b3; y2[idx*5+4] = b4;
    y12[(size_t)idx*8+0] = a0; y12[(size_t)idx*8+1] = a1;
    y12[(size_t)idx*8+2] = a2; y12[(size_t)idx*8+3] = b0;
    y12[(size_t)idx*8+4] = b1; y12[(size_t)idx*8+5] = b2;
    y12[(size_t)idx*8+6] = b3; y12[(size_t)idx*8+7] = b4;
  }
}

__global__ void copy_kernel(const float* __restrict__ a, float* __restrict__ b, int n)
{
  int i = blockIdx.x * 256 + threadIdx.x;
  if (i < n) b[i] = a[i];
}

__global__ void addinj_kernel(float* __restrict__ x, const float* __restrict__ inj, int n)
{
  int i = blockIdx.x * 256 + threadIdx.x;
  if (i < n) x[i] += inj[i];
}

__global__ void cvt128_kernel(const float* __restrict__ a, bf16* __restrict__ b)
{
  int i = blockIdx.x * 256 + threadIdx.x;
  if (i < NN * 128) b[i] = __float2bfloat16(a[i]);
}

// ---------------------------------------------------------------- equivariant LN
// Outputs planar bf16 (GEMM A-operand) and, when xrec != nullptr, the
// attn-packed node records:
//   xrec [n][64][8]: slots {s0, s1, v1_0, v1_1, v1_2, sp1(later)} per lane t
//   xrec2[n][32][8]: slots {v2_0..v2_4, sp2(later)}             per lane t32
__global__ __launch_bounds__(64)
void ln_kernel(const float* __restrict__ x, bf16* __restrict__ ob,
               bf16* __restrict__ xrec, bf16* __restrict__ xrec2)
{
  int n = blockIdx.x, t = threadIdx.x;
  bool lo = t < 32;
  int t32 = t & 31;
  float s0 = x[n*128 + t], s1 = x[n*128 + 64 + t];
  float v1v[3], v2v[5];
  #pragma unroll
  for (int m = 0; m < 3; m++) v1v[m] = x[V1_OFF + m*NN*64 + n*64 + t];
  #pragma unroll
  for (int m = 0; m < 5; m++) v2v[m] = lo ? x[V2_OFF + m*NN*32 + n*32 + t32] : 0.f;
  float ssum = s0 + s1, ssq = s0*s0 + s1*s1;
  float q1 = v1v[0]*v1v[0] + v1v[1]*v1v[1] + v1v[2]*v1v[2];
  float q2 = 0.f;
  #pragma unroll
  for (int m = 0; m < 5; m++) q2 += v2v[m]*v2v[m];
  #pragma unroll
  for (int d = 32; d >= 1; d >>= 1) {
    ssum += __shfl_xor(ssum, d);
    ssq  += __shfl_xor(ssq, d);
    q1   += __shfl_xor(q1, d);
    q2   += __shfl_xor(q2, d);
  }
  float mu  = ssum * (1.f/128.f);
  float var = fmaxf(ssq * (1.f/128.f) - mu*mu, 0.f);
  float is  = rsqrtf(var + 1e-5f);
  float i1  = rsqrtf(q1 * (1.f/64.f) + 1e-5f);
  float i2  = rsqrtf(q2 * (1.f/32.f) + 1e-5f);
  float os0 = (s0 - mu) * is, os1 = (s1 - mu) * is;
  float ov1[3], ov2[5];
  #pragma unroll
  for (int m = 0; m < 3; m++) ov1[m] = v1v[m] * i1;
  #pragma unroll
  for (int m = 0; m < 5; m++) ov2[m] = v2v[m] * i2;
  ob[n*128 + t]      = __float2bfloat16(os0);
  ob[n*128 + 64 + t] = __float2bfloat16(os1);
  #pragma unroll
  for (int m = 0; m < 3; m++)
    ob[V1_OFF + m*NN*64 + n*64 + t] = __float2bfloat16(ov1[m]);
  if (lo) {
    #pragma unroll
    for (int m = 0; m < 5; m++)
      ob[V2_OFF + m*NN*32 + n*32 + t32] = __float2bfloat16(ov2[m]);
  }
  if (xrec) {
    short8 r;
    r[0] = f2b(os0); r[1] = f2b(os1);
    r[2] = f2b(ov1[0]); r[3] = f2b(ov1[1]); r[4] = f2b(ov1[2]);
    r[5] = 0; r[6] = 0; r[7] = 0;
    *reinterpret_cast<short8*>(xrec + (size_t)n*512 + t*8) = r;
    if (lo) {
      short8 r2;
      r2[0] = f2b(ov2[0]); r2[1] = f2b(ov2[1]); r2[2] = f2b(ov2[2]);
      r2[3] = f2b(ov2[3]); r2[4] = f2b(ov2[4]);
      r2[5] = 0; r2[6] = 0; r2[7] = 0;
      *reinterpret_cast<short8*>(xrec2 + (size_t)n*256 + t32*8) = r2;
    }
  }
}

// ---------------------------------------------------------------- degree embedding
__global__ __launch_bounds__(64)
void deg_inj_kernel(const int* __restrict__ indptr, const int* __restrict__ srcp,
                    const bf16* __restrict__ wd,
                    const float* __restrict__ s_atom, const float* __restrict__ spd1,
                    const float* __restrict__ spd2, const float* __restrict__ y1,
                    const float* __restrict__ y2, float* __restrict__ inj)
{
  int n = blockIdx.x, t = threadIdx.x;
  bool lo = t < 32;
  int t32 = t & 31;
  float acc0 = 0, acc1 = 0, a1[3] = {0,0,0}, a2[5] = {0,0,0,0,0};
  int beg = indptr[n], end = indptr[n+1];
  for (int idx = beg; idx < end; ++idx) {
    int s = srcp[idx];
    const bf16* we = wd + (size_t)idx * 320;
    acc0 += s_atom[s*128 + t]      * ldw(&we[t]);
    acc1 += s_atom[s*128 + 64 + t] * ldw(&we[64 + t]);
    float sp1e = spd1[s*64 + t];
    float w2k = ldw(&we[192 + t]);
    #pragma unroll
    for (int m = 0; m < 3; m++) a1[m] += sp1e * y1[idx*3+m] * w2k;
    float sp2e = lo ? spd2[s*32 + t32] : 0.f;
    float w4k  = lo ? ldw(&we[288 + t32]) : 0.f;
    #pragma unroll
    for (int m = 0; m < 5; m++) a2[m] += sp2e * y2[idx*5+m] * w4k;
  }
  const float inv = 0.25f;  // 1/sqrt(AVG_DEGREE=16)
  inj[n*128 + t]      = s_atom[n*128 + t]      + acc0 * inv;
  inj[n*128 + 64 + t] = s_atom[n*128 + 64 + t] + acc1 * inv;
  #pragma unroll
  for (int m = 0; m < 3; m++) inj[V1_OFF + m*NN*64 + n*64 + t] = a1[m] * inv;
  if (lo) {
    #pragma unroll
    for (int m = 0; m < 5; m++) inj[V2_OFF + m*NN*32 + n*32 + t32] = a2[m] * inv;
  }
}

// ---------------------------------------------------------------- fused attention
// R17-best + sp folded into records: per edge {w8, l4, xrec8(+sp1), xrec2(+sp2),
// ya, yb} — 6 loads, 4 base-address chains.
__global__ __launch_bounds__(64)
void attn_kernel(const int* __restrict__ norder,
                 const int* __restrict__ indptr, const int* __restrict__ srcp,
                 const bf16* __restrict__ w,
                 const bf16* __restrict__ xrec, const bf16* __restrict__ xrec2,
                 const bf16* __restrict__ qcat,
                 const bf16* __restrict__ qv1b, const bf16* __restrict__ qv2b,
                 const float* __restrict__ y12,
                 bf16* __restrict__ att)
{
  int n = norder[blockIdx.x];
  int t = threadIdx.x;
  bool lo = t < 32;
  int t32 = t & 31;
  const float qscl = 0.09128709291752769f;   // 1/sqrt(HD=120)
  float qs0 = ldw(&qcat[n*128 + t]) * qscl, qs1 = ldw(&qcat[n*128 + 64 + t]) * qscl;
  float qv1[3], qv2[5];
  #pragma unroll
  for (int m = 0; m < 3; m++) qv1[m] = ldw(&qv1b[m*NN*64 + n*64 + t]) * qscl;
  #pragma unroll
  for (int m = 0; m < 5; m++) qv2[m] = lo ? ldw(&qv2b[m*NN*32 + n*32 + t32]) * qscl : 0.f;
  const int h_s0 = t >> 5, h_s1 = 2 + (t >> 5), h_v1 = t >> 4, h_v2 = t32 >> 3;
  float m_run[4] = {-1e30f, -1e30f, -1e30f, -1e30f};
  float d_run[4] = {0, 0, 0, 0};
  float as0 = 0, as1 = 0, av1[3] = {0,0,0}, av2[5] = {0,0,0,0,0};
  int beg = indptr[n], end = indptr[n+1];
  for (int idx = beg; idx < end; ++idx) {
    int s = srcp[idx];
    const bf16* we = w + (size_t)idx * 640;
    // packed weights: one 16B load (full-wave) + one 8B load (lo lanes)
    short8 w8 = *reinterpret_cast<const short8*>(we + t*8);
    float kw0 = b2f(w8[0]), kw1 = b2f(w8[1]), w1k = b2f(w8[2]), w2k = b2f(w8[3]);
    float vw0 = b2f(w8[4]), vw1 = b2f(w8[5]), w1v = b2f(w8[6]), w2v = b2f(w8[7]);
    float w3k = 0, w4k = 0, w3v = 0, w4v = 0;
    if (lo) {
      short4v l4 = *reinterpret_cast<const short4v*>(we + 512 + t32*4);
      w3k = b2f(l4[0]); w4k = b2f(l4[1]); w3v = b2f(l4[2]); w4v = b2f(l4[3]);
    }
    // packed node record: one 16B load replaces 6 gathers (incl. sp1)
    short8 xr = *reinterpret_cast<const short8*>(xrec + (size_t)s*512 + t*8);
    float sE0 = b2f(xr[0]), sE1 = b2f(xr[1]);
    float v1E[3] = {b2f(xr[2]), b2f(xr[3]), b2f(xr[4])};
    float sp1e = b2f(xr[5]);
    float v2E[5] = {0,0,0,0,0};
    float sp2e = 0;
    if (lo) {
      short8 xr2 = *reinterpret_cast<const short8*>(xrec2 + (size_t)s*256 + t32*8);
      v2E[0] = b2f(xr2[0]); v2E[1] = b2f(xr2[1]); v2E[2] = b2f(xr2[2]);
      v2E[3] = b2f(xr2[3]); v2E[4] = b2f(xr2[4]);
      sp2e = b2f(xr2[5]);
    }
    // packed spherical harmonics: 2 vector loads replace 8 scalar loads
    float4 ya = *reinterpret_cast<const float4*>(&y12[(size_t)idx*8]);
    float Y1[3] = {ya.x, ya.y, ya.z};
    float Y2[5] = {0,0,0,0,0};
    if (lo) {
      float4 yb = *reinterpret_cast<const float4*>(&y12[(size_t)idx*8 + 4]);
      Y2[0] = ya.w; Y2[1] = yb.x; Y2[2] = yb.y; Y2[3] = yb.z; Y2[4] = yb.w;
    }
    // ---- logits
    float part[4] = {0,0,0,0};
    part[h_s0] += qs0 * (sE0 * kw0);
    part[h_s1] += qs1 * (sE1 * kw1);
    #pragma unroll
    for (int m = 0; m < 3; m++) part[h_v1] += qv1[m] * (v1E[m]*w1k + sp1e*Y1[m]*w2k);
    #pragma unroll
    for (int m = 0; m < 5; m++) part[h_v2] += qv2[m] * (v2E[m]*w3k + sp2e*Y2[m]*w4k);
    #pragma unroll
    for (int d = 1; d < 64; d <<= 1) {
      #pragma unroll
      for (int h = 0; h < 4; h++) part[h] += __shfl_xor(part[h], d);
    }
    // ---- defer-max: rescale only when a logit exceeds running max + 8
    if (part[0] > m_run[0] + 8.f || part[1] > m_run[1] + 8.f ||
        part[2] > m_run[2] + 8.f || part[3] > m_run[3] + 8.f) {
      float scl[4];
      #pragma unroll
      for (int h = 0; h < 4; h++) {
        float nm = fmaxf(m_run[h], part[h]);
        scl[h] = __expf(m_run[h] - nm);
        m_run[h] = nm;
        d_run[h] *= scl[h];
      }
      as0 *= scl[h_s0]; as1 *= scl[h_s1];
      #pragma unroll
      for (int m = 0; m < 3; m++) av1[m] *= scl[h_v1];
      #pragma unroll
      for (int m = 0; m < 5; m++) av2[m] *= scl[h_v2];
    }
    float pp[4];
    #pragma unroll
    for (int h = 0; h < 4; h++) { pp[h] = __expf(part[h] - m_run[h]); d_run[h] += pp[h]; }
    // ---- accumulate v
    as0 += pp[h_s0] * (sE0 * vw0);
    as1 += pp[h_s1] * (sE1 * vw1);
    #pragma unroll
    for (int m = 0; m < 3; m++)
      av1[m] += pp[h_v1] * (v1E[m]*w1v + sp1e*Y1[m]*w2v);
    #pragma unroll
    for (int m = 0; m < 5; m++)
      av2[m] += pp[h_v2] * (v2E[m]*w3v + sp2e*Y2[m]*w4v);
  }
  float r0 = 1.f / (d_run[h_s0] + 1e-9f);
  float r1 = 1.f / (d_run[h_s1] + 1e-9f);
  att[n*128 + t]      = __float2bfloat16(as0 * r0);
  att[n*128 + 64 + t] = __float2bfloat16(as1 * r1);
  float rv1 = 1.f / (d_run[h_v1] + 1e-9f);
  #pragma unroll
  for (int m = 0; m < 3; m++)
    att[V1_OFF + m*NN*64 + n*64 + t] = __float2bfloat16(av1[m] * rv1);
  if (lo) {
    float rv2 = 1.f / (d_run[h_v2] + 1e-9f);
    #pragma unroll
    for (int m = 0; m < 5; m++)
      att[V2_OFF + m*NN*32 + n*32 + t32] = __float2bfloat16(av2[m] * rv2);
  }
}

// ---------------------------------------------------------------- gating
// ycat = [ys(128) | g_pre(96)] bf16, ld 224. ybs = silu(ys) bf16; yv1/yv2 *= sigmoid(g).
__global__ void gate_kernel(const bf16* __restrict__ ycat, bf16* __restrict__ ybs,
                            bf16* __restrict__ yv1, bf16* __restrict__ yv2)
{
  int idx = blockIdx.x * 256 + threadIdx.x;
  if (idx >= NN * 480) return;
  if (idx < NN * 128) {
    int n = idx >> 7, c = idx & 127;
    float v = ldw(&ycat[n*224 + c]);
    ybs[idx] = __float2bfloat16(v / (1.f + expf(-v)));
  } else if (idx < NN * 320) {
    int rel = idx - NN * 128;
    int n = (rel % (NN * 64)) / 64;
    int c = rel % 64;
    float g = ldw(&ycat[n*224 + 128 + c]);
    g = 1.f / (1.f + expf(-g));
    yv1[rel] = __float2bfloat16(__bfloat162float(yv1[rel]) * g);
  } else {
    int rel = idx - NN * 320;
    int n = (rel % (NN * 32)) / 32;
    int c = rel % 32;
    float g = ldw(&ycat[n*224 + 192 + c]);
    g = 1.f / (1.f + expf(-g));
    yv2[rel] = __float2bfloat16(__bfloat162float(yv2[rel]) * g);
  }
}

// ---------------------------------------------------------------- readout
__global__ __launch_bounds__(64)
void ln512_kernel(float* __restrict__ f, bf16* __restrict__ fb)
{
  int n = blockIdx.x, t = threadIdx.x;
  float v[8];
  float s = 0, sq = 0;
  #pragma unroll
  for (int i = 0; i < 8; i++) {
    v[i] = f[(long)n*512 + i*64 + t];
    s += v[i]; sq += v[i]*v[i];
  }
  #pragma unroll
  for (int d = 32; d >= 1; d >>= 1) { s += __shfl_xor(s, d); sq += __shfl_xor(sq, d); }
  float mu  = s * (1.f/512.f);
  float var = fmaxf(sq * (1.f/512.f) - mu*mu, 0.f);
  float inv = rsqrtf(var + 1e-5f);
  #pragma unroll
  for (int i = 0; i < 8; i++) {
    float o = (v[i] - mu) * inv;
    fb[(long)n*512 + i*64 + t] = __float2bfloat16(o);
  }
}

__global__ __launch_bounds__(64)
void dot_seg_kernel(const float* __restrict__ h, const float* __restrict__ w2,
                    const int* __restrict__ bseg, float* __restrict__ out)
{
  int n = blockIdx.x, t = threadIdx.x;
  float acc = 0;
  #pragma unroll
  for (int i = 0; i < 8; i++) {
    int j = i*64 + t;
    acc += h[(long)n*512 + j] * w2[j];
  }
  #pragma unroll
  for (int d = 32; d >= 1; d >>= 1) acc += __shfl_xor(acc, d);
  if (t == 0) atomicAdd(&out[bseg[n]], acc * 0.21821789023599236f); // 1/sqrt(21)
}

// ---------------------------------------------------------------- host
extern "C" void kernel_launch(void* const* d_in, const int* in_sizes, int n_in,
                              void* d_out, int out_size, void* d_ws, size_t ws_size,
                              hipStream_t stream)
{
  const float* pos        = (const float*)d_in[0];
  const int*   atom_z     = (const int*)  d_in[1];
  const int*   esrc       = (const int*)  d_in[2];
  const int*   edst       = (const int*)  d_in[3];
  const int*   bseg       = (const int*)  d_in[4];
  const float* atom_table = (const float*)d_in[5];
  const float* Pd1 = (const float*)d_in[6];
  const float* Pd2 = (const float*)d_in[7];
  const float* Rd1 = (const float*)d_in[8];
  const float* Rd2 = (const float*)d_in[9];
  const float* Rd3 = (const float*)d_in[10];
  const float* Wq0 = (const float*)d_in[11];
  const float* Wq1 = (const float*)d_in[12];
  const float* Wq2 = (const float*)d_in[13];
  const float* P1  = (const float*)d_in[14];
  const float* P2  = (const float*)d_in[15];
  const float* R1  = (const float*)d_in[16];
  const float* R2  = (const float*)d_in[17];
  const float* R3  = (const float*)d_in[18];
  const float* Wp0 = (const float*)d_in[19];
  const float* Wp1 = (const float*)d_in[20];
  const float* Wp2 = (const float*)d_in[21];
  const float* Wg  = (const float*)d_in[22];
  const float* Wi0 = (const float*)d_in[23];
  const float* Wi1 = (const float*)d_in[24];
  const float* Wi2 = (const float*)d_in[25];
  const float* Wo0 = (const float*)d_in[26];
  const float* Wo1 = (const float*)d_in[27];
  const float* Wo2 = (const float*)d_in[28];
  const float* Wf  = (const float*)d_in[29];
  const float* Wh1 = (const float*)d_in[30];
  const float* Wh2 = (const float*)d_in[31];
  (void)in_sizes; (void)n_in;

  // bump allocator over workspace (ws ~256 MiB)
  char* p = (char*)d_ws;
  auto allocB = [&](size_t bytes) -> void* {
    void* r = (void*)p;
    p += (bytes + 255) & ~(size_t)255;
    return r;
  };
  auto allocF = [&](size_t nf) -> float* { return (float*)allocB(nf * 4); };
  auto allocH = [&](size_t nh) -> bf16*  { return (bf16*)allocB(nh * 2); };

  bf16*  rbf   = allocH((size_t)NE * 128);
  float* y1    = allocF((size_t)NE * 3);
  float* y2    = allocF((size_t)NE * 5);
  float* y12   = allocF((size_t)NE * 8);
  bf16*  h1    = allocH((size_t)NE * 64);
  bf16*  h2c   = allocH((size_t)6 * NE * 64);   // cached radial h2 per block (38.4 MB)
  float* s_at  = allocF((size_t)NN * 128);
  bf16*  s_atb = allocH((size_t)NN * 128);
  float* inj   = allocF((size_t)NN * 480);
  float* x     = allocF((size_t)NN * 480);
  bf16*  xnb   = allocH((size_t)NN * 480);
  bf16*  xrec  = allocH((size_t)NN * 512);   // attn-packed node record (full-wave)
  bf16*  xrec2 = allocH((size_t)NN * 256);   // attn-packed node record (lo lanes)
  bf16*  qcat  = allocH((size_t)NN * 128);   // q scalars only (sp folded into records)
  bf16*  qv1   = allocH((size_t)NN * 192);
  bf16*  qv2   = allocH((size_t)NN * 160);
  bf16*  attb  = allocH((size_t)NN * 480);
  bf16*  ybs   = allocH((size_t)NN * 128);
  int* counts  = (int*)allocB((size_t)NN * 4);
  int* indptr  = (int*)allocB((size_t)(NN + 1) * 4);
  int* nextp   = (int*)allocB((size_t)NN * 4);
  int* order   = (int*)allocB((size_t)NE * 4);
  int* srcp    = (int*)allocB((size_t)NE * 4);
  int* norder  = (int*)allocB((size_t)NN * 4);
  int* dbins   = (int*)allocB((size_t)MAXD * 4);
  int* dboff   = (int*)allocB((size_t)MAXD * 4);
  float* spd1  = allocF((size_t)NN * 64);   // degree phase only
  float* spd2  = allocF((size_t)NN * 32);

  // lifetime aliases
  bf16*  ycat = attb;               // attb dead after Wp launch3; FFN cat output
  bf16*  yv1  = qv1;
  bf16*  yv2  = qv2;
  bf16*  xsb  = s_atb;              // s_atb dead after precompute

  // bf16 transposed weights
  bf16* Pd1t = allocH(64*128);
  bf16* Pd2t = allocH(32*128);
  bf16* Rd1t = allocH(64*128);
  bf16* Rd2t = allocH(64*64);
  bf16* Rd3t = allocH(320*64);
  bf16* catq = allocH((size_t)6*224*128);   // [Wq0^T | P1^T | P2^T]
  bf16* Wq1t = allocH((size_t)6*64*64);
  bf16* Wq2t = allocH((size_t)6*32*32);
  bf16* R1t  = allocH((size_t)6*64*128);
  bf16* R2t  = allocH((size_t)6*64*64);
  bf16* R3t  = allocH((size_t)6*640*64);    // PACKED-PERMUTED for attn
  bf16* Wp0t = allocH((size_t)6*128*128);
  bf16* Wp1t = allocH((size_t)6*64*64);
  bf16* Wp2t = allocH((size_t)6*32*32);
  bf16* cati = allocH((size_t)6*224*128);   // [Wi0^T | Wg^T]
  bf16* Wi1t = allocH((size_t)6*64*64);
  bf16* Wi2t = allocH((size_t)6*32*32);
  bf16* Wo0t = allocH((size_t)6*128*128);
  bf16* Wo1t = allocH((size_t)6*64*64);
  bf16* Wo2t = allocH((size_t)6*32*32);
  bf16* Wft  = allocH(512*128);
  bf16* Wh1t = allocH((size_t)512*512);

  size_t used = (size_t)(p - (char*)d_ws);
  size_t avail = (ws_size > used) ? ws_size - used : 0;
  const size_t slotH = (size_t)NE * 640 * sizeof(bf16);   // 61 MiB

  if (avail < slotH) {
    hipMemsetAsync(d_out, 0, (size_t)out_size * 4, stream);
    return;
  }
  bf16* w = (bf16*)allocB(slotH);   // single modulate-weight slot

  // readout buffers live in the w slot (dead by readout time)
  float* feat  = (float*)w;
  bf16*  featb = (bf16*)(feat + (size_t)NN*512);
  float* hb    = (float*)(featb + (size_t)NN*512);

  auto transp = [&](const float* src, bf16* dst, int R, int C, long sSrc, long sDst, int nz) {
    dim3 g((R*C + 255)/256, 1, nz);
    transp_kernel<<<g, 256, 0, stream>>>(src, dst, R, C, sSrc, sDst);
  };
  auto gemmF = [&](const bf16* A, const bf16* Bt, float* C, int M, int Nn, int K,
                   int lda, int ldc, int epi) {
    dim3 g((M + 63) / 64, (Nn + 63) / 64, 1);
    mgemm_kernel<float><<<g, 256, 0, stream>>>(A, Bt, C, M, Nn, K, lda, ldc, epi);
  };
  auto gemmH = [&](const bf16* A, const bf16* Bt, bf16* C, int M, int Nn, int K,
                   int lda, int ldc, int epi) {
    dim3 g((M + 63) / 64, (Nn + 63) / 64, 1);
    mgemm_kernel<bf16><<<g, 256, 0, stream>>>(A, Bt, C, M, Nn, K, lda, ldc, epi);
  };
  auto mkseg = [&](const bf16* A, const bf16* Bt, void* C, int M, int N, int K,
                   int lda, int ldc, int epi, int outBf16) -> GSeg {
    GSeg g; g.A = A; g.Bt = Bt; g.C = (char*)C; g.aux1 = nullptr; g.aux2 = nullptr;
    g.M = M; g.N = N; g.K = K;
    g.lda = lda; g.ldc = ldc; g.epi = epi; g.outBf16 = outBf16;
    g.blk0 = 0; g.nbx = (M + 63) / 64;
    return g;
  };
  auto segBlocks = [&](const GSeg& s) -> int { return s.nbx * ((s.N + 63) / 64); };
  auto launch3 = [&](GSeg a, GSeg b, GSeg c) {
    a.blk0 = 0;
    b.blk0 = segBlocks(a);
    c.blk0 = b.blk0 + segBlocks(b);
    int total = c.blk0 + segBlocks(c);
    gseg_kernel<<<total, 256, 0, stream>>>(a, b, c, c, 3);
  };
  auto launch4 = [&](GSeg a, GSeg b, GSeg c, GSeg d) {
    a.blk0 = 0;
    b.blk0 = segBlocks(a);
    c.blk0 = b.blk0 + segBlocks(b);
    d.blk0 = c.blk0 + segBlocks(c);
    int total = d.blk0 + segBlocks(d);
    gseg_kernel<<<total, 256, 0, stream>>>(a, b, c, d, 4);
  };

  // ------------ weight prep (bf16 transposed copies)
  transp(Pd1, Pd1t, 128, 64, 0, 0, 1);
  transp(Pd2, Pd2t, 128, 32, 0, 0, 1);
  transp(Rd1, Rd1t, 128, 64, 0, 0, 1);
  transp(Rd2, Rd2t, 64, 64, 0, 0, 1);
  transp(Rd3, Rd3t, 64, 320, 0, 0, 1);
  transp(Wq0, catq,           128, 128, 128*128, 224*128, 6);
  transp(P1,  catq + 128*128, 128, 64,  128*64,  224*128, 6);
  transp(P2,  catq + 192*128, 128, 32,  128*32,  224*128, 6);
  transp(Wq1, Wq1t, 64, 64, 64*64, 64*64, 6);
  transp(Wq2, Wq2t, 32, 32, 32*32, 32*32, 6);
  transp(R1,  R1t, 128, 64, 128*64, 128*64, 6);
  transp(R2,  R2t, 64, 64, 64*64, 64*64, 6);
  transp_r3_kernel<<<(NBLK*640*64 + 255)/256, 256, 0, stream>>>(R3, R3t);
  transp(Wp0, Wp0t, 128, 128, 128*128, 128*128, 6);
  transp(Wp1, Wp1t, 64, 64, 64*64, 64*64, 6);
  transp(Wp2, Wp2t, 32, 32, 32*32, 32*32, 6);
  transp(Wi0, cati,           128, 128, 128*128, 224*128, 6);
  transp(Wg,  cati + 128*128, 128, 96,  128*96,  224*128, 6);
  transp(Wi1, Wi1t, 64, 64, 64*64, 64*64, 6);
  transp(Wi2, Wi2t, 32, 32, 32*32, 32*32, 6);
  transp(Wo0, Wo0t, 128, 128, 128*128, 128*128, 6);
  transp(Wo1, Wo1t, 64, 64, 64*64, 64*64, 6);
  transp(Wo2, Wo2t, 32, 32, 32*32, 32*32, 6);
  transp(Wf,  Wft, 128, 512, 0, 0, 1);
  transp(Wh1, Wh1t, 512, 512, 0, 0, 1);

  // ------------ precompute
  hipMemsetAsync(counts, 0, NN * 4, stream);
  hipMemsetAsync(dbins, 0, MAXD * 4, stream);
  hipMemsetAsync(d_out, 0, (size_t)out_size * 4, stream);
  gather_atom_kernel<<<(NN*128 + 255)/256, 256, 0, stream>>>(atom_z, atom_table, s_at, s_atb);
  hist_kernel<<<(NE + 255)/256, 256, 0, stream>>>(edst, counts);
  scan_kernel<<<1, 1024, 0, stream>>>(counts, indptr, nextp);
  scatter_kernel<<<(NE + 255)/256, 256, 0, stream>>>(edst, nextp, order);
  edge_perm_kernel<<<NE, 128, 0, stream>>>(pos, esrc, edst, order, srcp, rbf, y1, y2, y12);
  // degree-descending node order for attn dispatch balance
  dhist_kernel<<<(NN + 255)/256, 256, 0, stream>>>(indptr, dbins);
  dscan_kernel<<<1, MAXD, 0, stream>>>(dbins, dboff);
  dplace_kernel<<<(NN + 255)/256, 256, 0, stream>>>(indptr, dboff, norder);
  gemmF(s_atb, Pd1t, spd1, NN, 64, 128, 128, 64, 0);
  gemmF(s_atb, Pd2t, spd2, NN, 32, 128, 128, 32, 0);
  // degree radial chain (uses h2c[0] as temp; refilled by pre-pass below)
  gemmH(rbf, Rd1t, h1, NE, 64, 128, 128, 64, 1);
  gemmH(h1,  Rd2t, h2c, NE, 64, 64, 64, 64, 1);
  gemmH(h2c, Rd3t, w,  NE, 320, 64, 64, 320, 0);   // wd uses UNPERMUTED Rd3t layout
  deg_inj_kernel<<<NN, 64, 0, stream>>>(indptr, srcp, w, s_at, spd1, spd2, y1, y2, inj);
  copy_kernel<<<(NN*480 + 255)/256, 256, 0, stream>>>(inj, x, NN*480);

  // radial h2 pre-pass: x-independent, compute once for all 6 blocks
  for (int i = 0; i < 6; i++) {
    gemmH(rbf, R1t + (size_t)i*64*128, h1, NE, 64, 128, 128, 64, 1);
    gemmH(h1,  R2t + (size_t)i*64*64, h2c + (size_t)i*NE*64, NE, 64, 64, 64, 64, 1);
  }

  auto run_block = [&](int i) {
    const bf16* cq  = catq + (size_t)i * 224 * 128;
    const bf16* q1t = Wq1t + (size_t)i * 64 * 64;
    const bf16* q2t = Wq2t + (size_t)i * 32 * 32;
    const bf16* r3  = R3t  + (size_t)i * 640 * 64;
    const bf16* p0t = Wp0t + (size_t)i * 128 * 128;
    const bf16* p1t = Wp1t + (size_t)i * 64 * 64;
    const bf16* p2t = Wp2t + (size_t)i * 32 * 32;
    const bf16* ci  = cati + (size_t)i * 224 * 128;
    const bf16* i1t = Wi1t + (size_t)i * 64 * 64;
    const bf16* i2t = Wi2t + (size_t)i * 32 * 32;
    const bf16* o0t = Wo0t + (size_t)i * 128 * 128;
    const bf16* o1t = Wo1t + (size_t)i * 64 * 64;
    const bf16* o2t = Wo2t + (size_t)i * 32 * 32;

    ln_kernel<<<NN, 64, 0, stream>>>(x, xnb, xrec, xrec2);
    // Q-group (qcat + sp->records via epi5 | qv1 | qv2) + modulate-weight GEMM
    GSeg sq = mkseg(xnb, cq, qcat, NN, 224, 128, 128, 128, 5, 1);
    sq.aux1 = (char*)xrec; sq.aux2 = (char*)xrec2;
    launch4(sq,
            mkseg(xnb + V1_OFF, q1t, qv1,  3*NN, 64,  64,  64,  64,  0, 1),
            mkseg(xnb + V2_OFF, q2t, qv2,  5*NN, 32,  32,  32,  32,  0, 1),
            mkseg(h2c + (size_t)i*NE*64, r3, w, NE, 640, 64, 64, 640, 0, 1));
    // fused online-softmax attention (packed w + y12 + xrec(+sp); defer-max)
    attn_kernel<<<NN, 64, 0, stream>>>(norder, indptr, srcp, w, xrec, xrec2, qcat, qv1, qv2, y12, attb);
    // x += eq_linear(att, Wp) (one dispatch)
    launch3(mkseg(attb,          p0t, x,          NN,   128, 128, 128, 128, 2, 0),
            mkseg(attb + V1_OFF, p1t, x + V1_OFF, 3*NN, 64,  64,  64,  64,  2, 0),
            mkseg(attb + V2_OFF, p2t, x + V2_OFF, 5*NN, 32,  32,  32,  32,  2, 0));
    // FFN (ycat aliases attb, now dead)
    ln_kernel<<<NN, 64, 0, stream>>>(x, xnb, nullptr, nullptr);
    launch3(mkseg(xnb,          ci,  ycat, NN,   224, 128, 128, 224, 0, 1),
            mkseg(xnb + V1_OFF, i1t, yv1,  3*NN, 64,  64,  64,  64,  0, 1),
            mkseg(xnb + V2_OFF, i2t, yv2,  5*NN, 32,  32,  32,  32,  0, 1));
    gate_kernel<<<(NN*480 + 255)/256, 256, 0, stream>>>(ycat, ybs, yv1, yv2);
    launch3(mkseg(ybs, o0t, x,          NN,   128, 128, 128, 128, 2, 0),
            mkseg(yv1, o1t, x + V1_OFF, 3*NN, 64,  64,  64,  64,  2, 0),
            mkseg(yv2, o2t, x + V2_OFF, 5*NN, 32,  32,  32,  32,  2, 0));
  };

  // ------------ DEQ unroll: z=0; twice {x = z + inj; 5 blocks}; then block 5
  for (int t = 0; t < 2; t++) {
    if (t == 1) addinj_kernel<<<(NN*480 + 255)/256, 256, 0, stream>>>(x, inj, NN*480);
    for (int i = 0; i < 5; i++) run_block(i);
  }
  run_block(5);

  // ------------ readout (feat/hb/featb live in the dead w slot)
  cvt128_kernel<<<(NN*128 + 255)/256, 256, 0, stream>>>(x, xsb);
  gemmF(xsb, Wft, feat, NN, 512, 128, 128, 512, 0);
  ln512_kernel<<<NN, 64, 0, stream>>>(feat, featb);
  gemmF(featb, Wh1t, hb, NN, 512, 512, 512, 512, 1);
  dot_seg_kernel<<<NN, 64, 0, stream>>>(hb, Wh2, bseg, (float*)d_out);
}

// Round 19
// 1777.460 us; speedup vs baseline: 1.0240x; 1.0240x over previous
//
#include <hip/hip_runtime.h>
#include <hip/hip_bf16.h>
#include <math.h>

// Problem constants
#define NN 10000      // nodes
#define NE 50000      // edges
#define NBLK 6
#define MAXD 256      // degree clamp for counting sort
// feature split: C0=128 scalars, C1=64 l1-vectors (3 comps), C2=32 l2-vectors (5 comps)
// planar layout inside a node-feature buffer of NN*480 elems:
//   S  at [0, NN*128)                 row-major N x 128
//   V1 plane m at NN*128 + m*NN*64    row-major N x 64, m=0..2
//   V2 plane m at NN*320 + m*NN*32    row-major N x 32, m=0..4
#define V1_OFF (NN*128)
#define V2_OFF (NN*320)

typedef __hip_bfloat16 bf16;
typedef __attribute__((ext_vector_type(8))) short short8;
typedef __attribute__((ext_vector_type(4))) short short4v;
typedef __attribute__((ext_vector_type(4))) float f32x4;

__device__ __forceinline__ float ldw(const float* p){ return *p; }
__device__ __forceinline__ float ldw(const bf16* p){ return __bfloat162float(*p); }
__device__ __forceinline__ void stw(float* p, float v){ *p = v; }
__device__ __forceinline__ void stw(bf16* p, float v){ *p = __float2bfloat16(v); }
__device__ __forceinline__ float b2f(short u){
  unsigned int x = ((unsigned int)(unsigned short)u) << 16;
  return __builtin_bit_cast(float, x);
}
__device__ __forceinline__ short f2b(float v){
  return __builtin_bit_cast(short, (unsigned short)(__builtin_bit_cast(unsigned int, v) >> 16 ));
}

// ---------------------------------------------------------------- MFMA GEMM
// C[M x Nn] = A[M x K] @ B; A bf16 row-major (lda); B PRE-TRANSPOSED bf16
// Bt[Nn x K] row-major (ld=K). f32 accumulate. K mult of 32.
// epi: 0=store, 1=silu, 2=accumulate into C, 3=sigmoid
template<typename OutT>
__global__ __launch_bounds__(256)
void mgemm_kernel(const bf16* __restrict__ A, const bf16* __restrict__ Bt,
                  OutT* __restrict__ C, int M, int Nn, int K,
                  int lda, int ldc, int epi)
{
  __shared__ __align__(16) unsigned short Ash[64][40];
  __shared__ __align__(16) unsigned short Bsh[64][40];
  int tid  = threadIdx.x;
  int wid  = tid >> 6, lane = tid & 63;
  int wr   = wid >> 1, wc = wid & 1;
  int rowBase = blockIdx.x * 64, colBase = blockIdx.y * 64;
  int fr = lane & 15;
  int fk = (lane >> 4) * 8;
  f32x4 acc[2][2] = {};
  int am = tid >> 2, ako = (tid & 3) * 8;

  for (int k0 = 0; k0 < K; k0 += 32) {
    {
      int gm = rowBase + am;
      short8 v = {0,0,0,0,0,0,0,0};
      if (gm < M) v = *reinterpret_cast<const short8*>(A + (long)gm * lda + k0 + ako);
      *reinterpret_cast<short8*>(&Ash[am][ako]) = v;
    }
    {
      int gn = colBase + am;
      short8 v = {0,0,0,0,0,0,0,0};
      if (gn < Nn) v = *reinterpret_cast<const short8*>(Bt + (long)gn * K + k0 + ako);
      *reinterpret_cast<short8*>(&Bsh[am][ako]) = v;
    }
    __syncthreads();
    short8 a0 = *reinterpret_cast<const short8*>(&Ash[wr*32 +      fr][fk]);
    short8 a1 = *reinterpret_cast<const short8*>(&Ash[wr*32 + 16 + fr][fk]);
    short8 b0 = *reinterpret_cast<const short8*>(&Bsh[wc*32 +      fr][fk]);
    short8 b1 = *reinterpret_cast<const short8*>(&Bsh[wc*32 + 16 + fr][fk]);
    acc[0][0] = __builtin_amdgcn_mfma_f32_16x16x32_bf16(a0, b0, acc[0][0], 0, 0, 0);
    acc[0][1] = __builtin_amdgcn_mfma_f32_16x16x32_bf16(a0, b1, acc[0][1], 0, 0, 0);
    acc[1][0] = __builtin_amdgcn_mfma_f32_16x16x32_bf16(a1, b0, acc[1][0], 0, 0, 0);
    acc[1][1] = __builtin_amdgcn_mfma_f32_16x16x32_bf16(a1, b1, acc[1][1], 0, 0, 0);
    __syncthreads();
  }
  int erow = (lane >> 4) * 4, ecol = lane & 15;
  #pragma unroll
  for (int tm = 0; tm < 2; tm++) {
    #pragma unroll
    for (int tn = 0; tn < 2; tn++) {
      #pragma unroll
      for (int r = 0; r < 4; r++) {
        int gm = rowBase + wr*32 + tm*16 + erow + r;
        int gn = colBase + wc*32 + tn*16 + ecol;
        if (gm < M && gn < Nn) {
          float v = acc[tm][tn][r];
          long off = (long)gm * ldc + gn;
          if (epi == 1)      v = v / (1.f + expf(-v));
          else if (epi == 2) v = v + ldw(&C[off]);
          else if (epi == 3) v = 1.f / (1.f + expf(-v));
          stw(&C[off], v);
        }
      }
    }
  }
}

// ---------------------------------------------------------------- grouped GEMM
// up to 4 independent segments in one dispatch (flattened tight grid)
struct GSeg {
  const bf16* A; const bf16* Bt; char* C;
  int M, N, K, lda, ldc, epi, outBf16, blk0, nbx;
};

__global__ __launch_bounds__(256)
void gseg_kernel(GSeg s0, GSeg s1, GSeg s2, GSeg s3, int nseg)
{
  GSeg s = s0;
  int b = blockIdx.x;
  if (nseg > 1 && b >= s1.blk0) s = s1;
  if (nseg > 2 && b >= s2.blk0) s = s2;
  if (nseg > 3 && b >= s3.blk0) s = s3;
  int rel = b - s.blk0;
  int bx = rel % s.nbx, by = rel / s.nbx;

  __shared__ __align__(16) unsigned short Ash[64][40];
  __shared__ __align__(16) unsigned short Bsh[64][40];
  int tid  = threadIdx.x;
  int wid  = tid >> 6, lane = tid & 63;
  int wr   = wid >> 1, wc = wid & 1;
  int rowBase = bx * 64, colBase = by * 64;
  int fr = lane & 15;
  int fk = (lane >> 4) * 8;
  f32x4 acc[2][2] = {};
  int am = tid >> 2, ako = (tid & 3) * 8;

  for (int k0 = 0; k0 < s.K; k0 += 32) {
    {
      int gm = rowBase + am;
      short8 v = {0,0,0,0,0,0,0,0};
      if (gm < s.M) v = *reinterpret_cast<const short8*>(s.A + (long)gm * s.lda + k0 + ako);
      *reinterpret_cast<short8*>(&Ash[am][ako]) = v;
    }
    {
      int gn = colBase + am;
      short8 v = {0,0,0,0,0,0,0,0};
      if (gn < s.N) v = *reinterpret_cast<const short8*>(s.Bt + (long)gn * s.K + k0 + ako);
      *reinterpret_cast<short8*>(&Bsh[am][ako]) = v;
    }
    __syncthreads();
    short8 a0 = *reinterpret_cast<const short8*>(&Ash[wr*32 +      fr][fk]);
    short8 a1 = *reinterpret_cast<const short8*>(&Ash[wr*32 + 16 + fr][fk]);
    short8 b0 = *reinterpret_cast<const short8*>(&Bsh[wc*32 +      fr][fk]);
    short8 b1 = *reinterpret_cast<const short8*>(&Bsh[wc*32 + 16 + fr][fk]);
    acc[0][0] = __builtin_amdgcn_mfma_f32_16x16x32_bf16(a0, b0, acc[0][0], 0, 0, 0);
    acc[0][1] = __builtin_amdgcn_mfma_f32_16x16x32_bf16(a0, b1, acc[0][1], 0, 0, 0);
    acc[1][0] = __builtin_amdgcn_mfma_f32_16x16x32_bf16(a1, b0, acc[1][0], 0, 0, 0);
    acc[1][1] = __builtin_amdgcn_mfma_f32_16x16x32_bf16(a1, b1, acc[1][1], 0, 0, 0);
    __syncthreads();
  }
  int erow = (lane >> 4) * 4, ecol = lane & 15;
  #pragma unroll
  for (int tm = 0; tm < 2; tm++) {
    #pragma unroll
    for (int tn = 0; tn < 2; tn++) {
      #pragma unroll
      for (int r = 0; r < 4; r++) {
        int gm = rowBase + wr*32 + tm*16 + erow + r;
        int gn = colBase + wc*32 + tn*16 + ecol;
        if (gm < s.M && gn < s.N) {
          float v = acc[tm][tn][r];
          long off = (long)gm * s.ldc + gn;
          if (s.epi == 1)      v = v / (1.f + expf(-v));
          else if (s.epi == 2) v = v + (s.outBf16 ? ldw((const bf16*)s.C + off)
                                                 : ldw((const float*)s.C + off));
          else if (s.epi == 3) v = 1.f / (1.f + expf(-v));
          if (s.outBf16) stw((bf16*)s.C + off, v);
          else           stw((float*)s.C + off, v);
        }
      }
    }
  }
}

// ---------------------------------------------------------------- transpose+cvt
__global__ void transp_kernel(const float* __restrict__ src, bf16* __restrict__ dst,
                              int R, int C, long sSrc, long sDst)
{
  src += (long)blockIdx.z * sSrc;
  dst += (long)blockIdx.z * sDst;
  int idx = blockIdx.x * 256 + threadIdx.x;
  if (idx < R * C) {
    int r = idx / C, c = idx - r * C;
    dst[(long)c * R + r] = __float2bfloat16(src[idx]);
  }
}

// R3 transpose with attn-packed column permutation:
// new col layout: [t*8+j] j=0..7 -> old cols {t,64+t,128+t,192+t,320+t,384+t,448+t,512+t}
//                 [512+t32*4+j] j=0..3 -> old cols {256+t32,288+t32,576+t32,608+t32}
__global__ void transp_r3_kernel(const float* __restrict__ src, bf16* __restrict__ dst)
{
  int idx = blockIdx.x * 256 + threadIdx.x;     // over NBLK*640*64
  if (idx >= NBLK * 640 * 64) return;
  int blk  = idx / (640 * 64);
  int rem  = idx - blk * 640 * 64;
  int newc = rem >> 6;          // dst row (0..639)
  int k    = rem & 63;          // dst col (K)
  int oldc;
  if (newc < 512) {
    int t = newc >> 3, j = newc & 7;
    const int base[8] = {0, 64, 128, 192, 320, 384, 448, 512};
    oldc = base[j] + t;
  } else {
    int q = newc - 512;
    int t32 = q >> 2, j = q & 3;
    const int base2[4] = {256, 288, 576, 608};
    oldc = base2[j] + t32;
  }
  dst[idx] = __float2bfloat16(src[(size_t)blk * 64 * 640 + (size_t)k * 640 + oldc]);
}

// ---------------------------------------------------------------- small kernels
__global__ void gather_atom_kernel(const int* __restrict__ z, const float* __restrict__ tab,
                                   float* __restrict__ s_atom, bf16* __restrict__ s_atom_bf)
{
  int idx = blockIdx.x * 256 + threadIdx.x;
  if (idx < NN * 128) {
    int n = idx >> 7, c = idx & 127;
    float v = tab[z[n] * 128 + c];
    s_atom[idx] = v;
    s_atom_bf[idx] = __float2bfloat16(v);
  }
}

__global__ void hist_kernel(const int* __restrict__ dst, int* __restrict__ counts)
{
  int e = blockIdx.x * 256 + threadIdx.x;
  if (e < NE) atomicAdd(&counts[dst[e]], 1);
}

__global__ __launch_bounds__(1024)
void scan_kernel(const int* __restrict__ counts, int* __restrict__ indptr,
                 int* __restrict__ nextp)
{
  __shared__ int totals[1024];
  const int PER = (NN + 1023) / 1024;   // 10
  int tid = threadIdx.x;
  int base = tid * PER;
  int local[PER];
  int s = 0;
  #pragma unroll
  for (int i = 0; i < PER; i++) {
    int idx = base + i;
    int c = (idx < NN) ? counts[idx] : 0;
    local[i] = s; s += c;
  }
  totals[tid] = s;
  __syncthreads();
  for (int off = 1; off < 1024; off <<= 1) {
    int v = (tid >= off) ? totals[tid - off] : 0;
    __syncthreads();
    totals[tid] += v;
    __syncthreads();
  }
  int prefix = (tid > 0) ? totals[tid - 1] : 0;
  #pragma unroll
  for (int i = 0; i < PER; i++) {
    int idx = base + i;
    if (idx < NN) { indptr[idx] = prefix + local[i]; nextp[idx] = prefix + local[i]; }
  }
  if (tid == 1023) indptr[NN] = totals[1023];
}

__global__ void scatter_kernel(const int* __restrict__ dst, int* __restrict__ nextp,
                               int* __restrict__ order)
{
  int e = blockIdx.x * 256 + threadIdx.x;
  if (e < NE) {
    int p = atomicAdd(&nextp[dst[e]], 1);
    order[p] = e;
  }
}

// ---- degree-descending node order (counting sort; output-order independent)
__global__ void dhist_kernel(const int* __restrict__ indptr, int* __restrict__ bins)
{
  int n = blockIdx.x * 256 + threadIdx.x;
  if (n < NN) {
    int d = indptr[n+1] - indptr[n]; if (d > MAXD-1) d = MAXD-1;
    atomicAdd(&bins[MAXD-1-d], 1);
  }
}
__global__ __launch_bounds__(256)
void dscan_kernel(const int* __restrict__ bins, int* __restrict__ boff)
{
  __shared__ int tmp[MAXD];
  int t = threadIdx.x;
  tmp[t] = bins[t];
  __syncthreads();
  for (int off = 1; off < MAXD; off <<= 1) {
    int v = (t >= off) ? tmp[t-off] : 0;
    __syncthreads();
    tmp[t] += v;
    __syncthreads();
  }
  boff[t] = tmp[t] - bins[t];
}
__global__ void dplace_kernel(const int* __restrict__ indptr, int* __restrict__ boff,
                              int* __restrict__ norder)
{
  int n = blockIdx.x * 256 + threadIdx.x;
  if (n < NN) {
    int d = indptr[n+1] - indptr[n]; if (d > MAXD-1) d = MAXD-1;
    int pos = atomicAdd(&boff[MAXD-1-d], 1);
    norder[pos] = n;
  }
}

// edge geometry, stored in CSR-permuted order (position idx = sorted-by-dst)
// y12: packed [y1[3] | y2[5]] per edge for attn vector loads
__global__ __launch_bounds__(128)
void edge_perm_kernel(const float* __restrict__ pos, const int* __restrict__ esrc,
                      const int* __restrict__ edst, const int* __restrict__ order,
                      int* __restrict__ srcp, bf16* __restrict__ rbf,
                      float* __restrict__ y1, float* __restrict__ y2,
                      float* __restrict__ y12)
{
  int idx = blockIdx.x, t = threadIdx.x;
  int e = order[idx];
  int s = esrc[e], d = edst[e];
  float vx = pos[d*3+0] - pos[s*3+0];
  float vy = pos[d*3+1] - pos[s*3+1];
  float vz = pos[d*3+2] - pos[s*3+2];
  float r = sqrtf(vx*vx + vy*vy + vz*vz + 1e-12f);
  float mu = t * (5.0f / 127.0f);
  const float inv_sig = 128.0f / 5.0f;
  float zq = (r - mu) * inv_sig;
  rbf[(long)idx * 128 + t] = __float2bfloat16(expf(-0.5f * zq * zq));
  if (t == 0) {
    srcp[idx] = s;
    float inv = 1.f / r;
    float ux = vx*inv, uy = vy*inv, uz = vz*inv;
    const float s3  = 1.7320508075688772f;   // sqrt(3)
    const float s15 = 3.872983346207417f;    // sqrt(15)
    float a0 = s3*ux, a1 = s3*uy, a2 = s3*uz;
    float b0 = s15*ux*uy;
    float b1 = s15*uy*uz;
    float b2 = 1.118033988749895f * (3.f*uz*uz - 1.f);   // sqrt(1.25)
    float b3 = s15*ux*uz;
    float b4 = 1.9364916731037085f * (ux*ux - uy*uy);    // sqrt(3.75)
    y1[idx*3+0] = a0; y1[idx*3+1] = a1; y1[idx*3+2] = a2;
    y2[idx*5+0] = b0; y2[idx*5+1] = b1; y2[idx*5+2] = b2;
    y2[idx*5+3] = b3; y2[idx*5+4] = b4;
    y12[(size_t)idx*8+0] = a0; y12[(size_t)idx*8+1] = a1;
    y12[(size_t)idx*8+2] = a2; y12[(size_t)idx*8+3] = b0;
    y12[(size_t)idx*8+4] = b1; y12[(size_t)idx*8+5] = b2;
    y12[(size_t)idx*8+6] = b3; y12[(size_t)idx*8+7] = b4;
  }
}

__global__ void copy_kernel(const float* __restrict__ a, float* __restrict__ b, int n)
{
  int i = blockIdx.x * 256 + threadIdx.x;
  if (i < n) b[i] = a[i];
}

__global__ void addinj_kernel(float* __restrict__ x, const float* __restrict__ inj, int n)
{
  int i = blockIdx.x * 256 + threadIdx.x;
  if (i < n) x[i] += inj[i];
}

__global__ void cvt128_kernel(const float* __restrict__ a, bf16* __restrict__ b)
{
  int i = blockIdx.x * 256 + threadIdx.x;
  if (i < NN * 128) b[i] = __float2bfloat16(a[i]);
}

// ---------------------------------------------------------------- equivariant LN
// Outputs planar bf16 (GEMM A-operand) and, when xrec != nullptr, the
// attn-packed node records:
//   xrec [n][64][8]: slots {s0, s1, v1_0, v1_1, v1_2} per lane t
//   xrec2[n][32][8]: slots {v2_0..v2_4}            per lane t32 (lo lanes)
__global__ __launch_bounds__(64)
void ln_kernel(const float* __restrict__ x, bf16* __restrict__ ob,
               bf16* __restrict__ xrec, bf16* __restrict__ xrec2)
{
  int n = blockIdx.x, t = threadIdx.x;
  bool lo = t < 32;
  int t32 = t & 31;
  float s0 = x[n*128 + t], s1 = x[n*128 + 64 + t];
  float v1v[3], v2v[5];
  #pragma unroll
  for (int m = 0; m < 3; m++) v1v[m] = x[V1_OFF + m*NN*64 + n*64 + t];
  #pragma unroll
  for (int m = 0; m < 5; m++) v2v[m] = lo ? x[V2_OFF + m*NN*32 + n*32 + t32] : 0.f;
  float ssum = s0 + s1, ssq = s0*s0 + s1*s1;
  float q1 = v1v[0]*v1v[0] + v1v[1]*v1v[1] + v1v[2]*v1v[2];
  float q2 = 0.f;
  #pragma unroll
  for (int m = 0; m < 5; m++) q2 += v2v[m]*v2v[m];
  #pragma unroll
  for (int d = 32; d >= 1; d >>= 1) {
    ssum += __shfl_xor(ssum, d);
    ssq  += __shfl_xor(ssq, d);
    q1   += __shfl_xor(q1, d);
    q2   += __shfl_xor(q2, d);
  }
  float mu  = ssum * (1.f/128.f);
  float var = fmaxf(ssq * (1.f/128.f) - mu*mu, 0.f);
  float is  = rsqrtf(var + 1e-5f);
  float i1  = rsqrtf(q1 * (1.f/64.f) + 1e-5f);
  float i2  = rsqrtf(q2 * (1.f/32.f) + 1e-5f);
  float os0 = (s0 - mu) * is, os1 = (s1 - mu) * is;
  float ov1[3], ov2[5];
  #pragma unroll
  for (int m = 0; m < 3; m++) ov1[m] = v1v[m] * i1;
  #pragma unroll
  for (int m = 0; m < 5; m++) ov2[m] = v2v[m] * i2;
  ob[n*128 + t]      = __float2bfloat16(os0);
  ob[n*128 + 64 + t] = __float2bfloat16(os1);
  #pragma unroll
  for (int m = 0; m < 3; m++)
    ob[V1_OFF + m*NN*64 + n*64 + t] = __float2bfloat16(ov1[m]);
  if (lo) {
    #pragma unroll
    for (int m = 0; m < 5; m++)
      ob[V2_OFF + m*NN*32 + n*32 + t32] = __float2bfloat16(ov2[m]);
  }
  if (xrec) {
    short8 r;
    r[0] = f2b(os0); r[1] = f2b(os1);
    r[2] = f2b(ov1[0]); r[3] = f2b(ov1[1]); r[4] = f2b(ov1[2]);
    r[5] = 0; r[6] = 0; r[7] = 0;
    *reinterpret_cast<short8*>(xrec + (size_t)n*512 + t*8) = r;
    if (lo) {
      short8 r2;
      r2[0] = f2b(ov2[0]); r2[1] = f2b(ov2[1]); r2[2] = f2b(ov2[2]);
      r2[3] = f2b(ov2[3]); r2[4] = f2b(ov2[4]);
      r2[5] = 0; r2[6] = 0; r2[7] = 0;
      *reinterpret_cast<short8*>(xrec2 + (size_t)n*256 + t32*8) = r2;
    }
  }
}

// ---------------------------------------------------------------- degree embedding
__global__ __launch_bounds__(64)
void deg_inj_kernel(const int* __restrict__ indptr, const int* __restrict__ srcp,
                    const bf16* __restrict__ wd,
                    const float* __restrict__ s_atom, const float* __restrict__ spd1,
                    const float* __restrict__ spd2, const float* __restrict__ y1,
                    const float* __restrict__ y2, float* __restrict__ inj)
{
  int n = blockIdx.x, t = threadIdx.x;
  bool lo = t < 32;
  int t32 = t & 31;
  float acc0 = 0, acc1 = 0, a1[3] = {0,0,0}, a2[5] = {0,0,0,0,0};
  int beg = indptr[n], end = indptr[n+1];
  for (int idx = beg; idx < end; ++idx) {
    int s = srcp[idx];
    const bf16* we = wd + (size_t)idx * 320;
    acc0 += s_atom[s*128 + t]      * ldw(&we[t]);
    acc1 += s_atom[s*128 + 64 + t] * ldw(&we[64 + t]);
    float sp1e = spd1[s*64 + t];
    float w2k = ldw(&we[192 + t]);
    #pragma unroll
    for (int m = 0; m < 3; m++) a1[m] += sp1e * y1[idx*3+m] * w2k;
    float sp2e = lo ? spd2[s*32 + t32] : 0.f;
    float w4k  = lo ? ldw(&we[288 + t32]) : 0.f;
    #pragma unroll
    for (int m = 0; m < 5; m++) a2[m] += sp2e * y2[idx*5+m] * w4k;
  }
  const float inv = 0.25f;  // 1/sqrt(AVG_DEGREE=16)
  inj[n*128 + t]      = s_atom[n*128 + t]      + acc0 * inv;
  inj[n*128 + 64 + t] = s_atom[n*128 + 64 + t] + acc1 * inv;
  #pragma unroll
  for (int m = 0; m < 3; m++) inj[V1_OFF + m*NN*64 + n*64 + t] = a1[m] * inv;
  if (lo) {
    #pragma unroll
    for (int m = 0; m < 5; m++) inj[V2_OFF + m*NN*32 + n*32 + t32] = a2[m] * inv;
  }
}

// ---------------------------------------------------------------- fused attention
// R17-best: 1 wave/node, online softmax, degree-sorted schedule, packed w,
// packed y12, packed xrec node records, defer-max rescale.
__global__ __launch_bounds__(64)
void attn_kernel(const int* __restrict__ norder,
                 const int* __restrict__ indptr, const int* __restrict__ srcp,
                 const bf16* __restrict__ w,
                 const bf16* __restrict__ xrec, const bf16* __restrict__ xrec2,
                 const bf16* __restrict__ qcat,
                 const bf16* __restrict__ qv1b, const bf16* __restrict__ qv2b,
                 const float* __restrict__ y12,
                 bf16* __restrict__ att)
{
  int n = norder[blockIdx.x];
  int t = threadIdx.x;
  bool lo = t < 32;
  int t32 = t & 31;
  const float qscl = 0.09128709291752769f;   // 1/sqrt(HD=120)
  float qs0 = ldw(&qcat[n*224 + t]) * qscl, qs1 = ldw(&qcat[n*224 + 64 + t]) * qscl;
  float qv1[3], qv2[5];
  #pragma unroll
  for (int m = 0; m < 3; m++) qv1[m] = ldw(&qv1b[m*NN*64 + n*64 + t]) * qscl;
  #pragma unroll
  for (int m = 0; m < 5; m++) qv2[m] = lo ? ldw(&qv2b[m*NN*32 + n*32 + t32]) * qscl : 0.f;
  const int h_s0 = t >> 5, h_s1 = 2 + (t >> 5), h_v1 = t >> 4, h_v2 = t32 >> 3;
  float m_run[4] = {-1e30f, -1e30f, -1e30f, -1e30f};
  float d_run[4] = {0, 0, 0, 0};
  float as0 = 0, as1 = 0, av1[3] = {0,0,0}, av2[5] = {0,0,0,0,0};
  int beg = indptr[n], end = indptr[n+1];
  for (int idx = beg; idx < end; ++idx) {
    int s = srcp[idx];
    const bf16* we = w + (size_t)idx * 640;
    // packed weights: one 16B load (full-wave) + one 8B load (lo lanes)
    short8 w8 = *reinterpret_cast<const short8*>(we + t*8);
    float kw0 = b2f(w8[0]), kw1 = b2f(w8[1]), w1k = b2f(w8[2]), w2k = b2f(w8[3]);
    float vw0 = b2f(w8[4]), vw1 = b2f(w8[5]), w1v = b2f(w8[6]), w2v = b2f(w8[7]);
    float w3k = 0, w4k = 0, w3v = 0, w4v = 0;
    if (lo) {
      short4v l4 = *reinterpret_cast<const short4v*>(we + 512 + t32*4);
      w3k = b2f(l4[0]); w4k = b2f(l4[1]); w3v = b2f(l4[2]); w4v = b2f(l4[3]);
    }
    // packed node record: one 16B load replaces 5 gathers
    short8 xr = *reinterpret_cast<const short8*>(xrec + (size_t)s*512 + t*8);
    float sE0 = b2f(xr[0]), sE1 = b2f(xr[1]);
    float v1E[3] = {b2f(xr[2]), b2f(xr[3]), b2f(xr[4])};
    float v2E[5] = {0,0,0,0,0};
    if (lo) {
      short8 xr2 = *reinterpret_cast<const short8*>(xrec2 + (size_t)s*256 + t32*8);
      v2E[0] = b2f(xr2[0]); v2E[1] = b2f(xr2[1]); v2E[2] = b2f(xr2[2]);
      v2E[3] = b2f(xr2[3]); v2E[4] = b2f(xr2[4]);
    }
    float sp1e = ldw(&qcat[s*224 + 128 + t]);
    float sp2e = lo ? ldw(&qcat[s*224 + 192 + t32]) : 0.f;
    // packed spherical harmonics: 2 vector loads replace 8 scalar loads
    float4 ya = *reinterpret_cast<const float4*>(&y12[(size_t)idx*8]);
    float Y1[3] = {ya.x, ya.y, ya.z};
    float Y2[5] = {0,0,0,0,0};
    if (lo) {
      float4 yb = *reinterpret_cast<const float4*>(&y12[(size_t)idx*8 + 4]);
      Y2[0] = ya.w; Y2[1] = yb.x; Y2[2] = yb.y; Y2[3] = yb.z; Y2[4] = yb.w;
    }
    // ---- logits
    float part[4] = {0,0,0,0};
    part[h_s0] += qs0 * (sE0 * kw0);
    part[h_s1] += qs1 * (sE1 * kw1);
    #pragma unroll
    for (int m = 0; m < 3; m++) part[h_v1] += qv1[m] * (v1E[m]*w1k + sp1e*Y1[m]*w2k);
    #pragma unroll
    for (int m = 0; m < 5; m++) part[h_v2] += qv2[m] * (v2E[m]*w3k + sp2e*Y2[m]*w4k);
    #pragma unroll
    for (int d = 1; d < 64; d <<= 1) {
      #pragma unroll
      for (int h = 0; h < 4; h++) part[h] += __shfl_xor(part[h], d);
    }
    // ---- defer-max: rescale only when a logit exceeds running max + 8
    if (part[0] > m_run[0] + 8.f || part[1] > m_run[1] + 8.f ||
        part[2] > m_run[2] + 8.f || part[3] > m_run[3] + 8.f) {
      float scl[4];
      #pragma unroll
      for (int h = 0; h < 4; h++) {
        float nm = fmaxf(m_run[h], part[h]);
        scl[h] = __expf(m_run[h] - nm);
        m_run[h] = nm;
        d_run[h] *= scl[h];
      }
      as0 *= scl[h_s0]; as1 *= scl[h_s1];
      #pragma unroll
      for (int m = 0; m < 3; m++) av1[m] *= scl[h_v1];
      #pragma unroll
      for (int m = 0; m < 5; m++) av2[m] *= scl[h_v2];
    }
    float pp[4];
    #pragma unroll
    for (int h = 0; h < 4; h++) { pp[h] = __expf(part[h] - m_run[h]); d_run[h] += pp[h]; }
    // ---- accumulate v
    as0 += pp[h_s0] * (sE0 * vw0);
    as1 += pp[h_s1] * (sE1 * vw1);
    #pragma unroll
    for (int m = 0; m < 3; m++)
      av1[m] += pp[h_v1] * (v1E[m]*w1v + sp1e*Y1[m]*w2v);
    #pragma unroll
    for (int m = 0; m < 5; m++)
      av2[m] += pp[h_v2] * (v2E[m]*w3v + sp2e*Y2[m]*w4v);
  }
  float r0 = 1.f / (d_run[h_s0] + 1e-9f);
  float r1 = 1.f / (d_run[h_s1] + 1e-9f);
  att[n*128 + t]      = __float2bfloat16(as0 * r0);
  att[n*128 + 64 + t] = __float2bfloat16(as1 * r1);
  float rv1 = 1.f / (d_run[h_v1] + 1e-9f);
  #pragma unroll
  for (int m = 0; m < 3; m++)
    att[V1_OFF + m*NN*64 + n*64 + t] = __float2bfloat16(av1[m] * rv1);
  if (lo) {
    float rv2 = 1.f / (d_run[h_v2] + 1e-9f);
    #pragma unroll
    for (int m = 0; m < 5; m++)
      att[V2_OFF + m*NN*32 + n*32 + t32] = __float2bfloat16(av2[m] * rv2);
  }
}

// ---------------------------------------------------------------- gating
// ycat = [ys(128) | g_pre(96)] bf16, ld 224. ybs = silu(ys) bf16; yv1/yv2 *= sigmoid(g).
__global__ void gate_kernel(const bf16* __restrict__ ycat, bf16* __restrict__ ybs,
                            bf16* __restrict__ yv1, bf16* __restrict__ yv2)
{
  int idx = blockIdx.x * 256 + threadIdx.x;
  if (idx >= NN * 480) return;
  if (idx < NN * 128) {
    int n = idx >> 7, c = idx & 127;
    float v = ldw(&ycat[n*224 + c]);
    ybs[idx] = __float2bfloat16(v / (1.f + expf(-v)));
  } else if (idx < NN * 320) {
    int rel = idx - NN * 128;
    int n = (rel % (NN * 64)) / 64;
    int c = rel % 64;
    float g = ldw(&ycat[n*224 + 128 + c]);
    g = 1.f / (1.f + expf(-g));
    yv1[rel] = __float2bfloat16(__bfloat162float(yv1[rel]) * g);
  } else {
    int rel = idx - NN * 320;
    int n = (rel % (NN * 32)) / 32;
    int c = rel % 32;
    float g = ldw(&ycat[n*224 + 192 + c]);
    g = 1.f / (1.f + expf(-g));
    yv2[rel] = __float2bfloat16(__bfloat162float(yv2[rel]) * g);
  }
}

// ---------------------------------------------------------------- readout
__global__ __launch_bounds__(64)
void ln512_kernel(float* __restrict__ f, bf16* __restrict__ fb)
{
  int n = blockIdx.x, t = threadIdx.x;
  float v[8];
  float s = 0, sq = 0;
  #pragma unroll
  for (int i = 0; i < 8; i++) {
    v[i] = f[(long)n*512 + i*64 + t];
    s += v[i]; sq += v[i]*v[i];
  }
  #pragma unroll
  for (int d = 32; d >= 1; d >>= 1) { s += __shfl_xor(s, d); sq += __shfl_xor(sq, d); }
  float mu  = s * (1.f/512.f);
  float var = fmaxf(sq * (1.f/512.f) - mu*mu, 0.f);
  float inv = rsqrtf(var + 1e-5f);
  #pragma unroll
  for (int i = 0; i < 8; i++) {
    float o = (v[i] - mu) * inv;
    fb[(long)n*512 + i*64 + t] = __float2bfloat16(o);
  }
}

__global__ __launch_bounds__(64)
void dot_seg_kernel(const float* __restrict__ h, const float* __restrict__ w2,
                    const int* __restrict__ bseg, float* __restrict__ out)
{
  int n = blockIdx.x, t = threadIdx.x;
  float acc = 0;
  #pragma unroll
  for (int i = 0; i < 8; i++) {
    int j = i*64 + t;
    acc += h[(long)n*512 + j] * w2[j];
  }
  #pragma unroll
  for (int d = 32; d >= 1; d >>= 1) acc += __shfl_xor(acc, d);
  if (t == 0) atomicAdd(&out[bseg[n]], acc * 0.21821789023599236f); // 1/sqrt(21)
}

// ---------------------------------------------------------------- host
extern "C" void kernel_launch(void* const* d_in, const int* in_sizes, int n_in,
                              void* d_out, int out_size, void* d_ws, size_t ws_size,
                              hipStream_t stream)
{
  const float* pos        = (const float*)d_in[0];
  const int*   atom_z     = (const int*)  d_in[1];
  const int*   esrc       = (const int*)  d_in[2];
  const int*   edst       = (const int*)  d_in[3];
  const int*   bseg       = (const int*)  d_in[4];
  const float* atom_table = (const float*)d_in[5];
  const float* Pd1 = (const float*)d_in[6];
  const float* Pd2 = (const float*)d_in[7];
  const float* Rd1 = (const float*)d_in[8];
  const float* Rd2 = (const float*)d_in[9];
  const float* Rd3 = (const float*)d_in[10];
  const float* Wq0 = (const float*)d_in[11];
  const float* Wq1 = (const float*)d_in[12];
  const float* Wq2 = (const float*)d_in[13];
  const float* P1  = (const float*)d_in[14];
  const float* P2  = (const float*)d_in[15];
  const float* R1  = (const float*)d_in[16];
  const float* R2  = (const float*)d_in[17];
  const float* R3  = (const float*)d_in[18];
  const float* Wp0 = (const float*)d_in[19];
  const float* Wp1 = (const float*)d_in[20];
  const float* Wp2 = (const float*)d_in[21];
  const float* Wg  = (const float*)d_in[22];
  const float* Wi0 = (const float*)d_in[23];
  const float* Wi1 = (const float*)d_in[24];
  const float* Wi2 = (const float*)d_in[25];
  const float* Wo0 = (const float*)d_in[26];
  const float* Wo1 = (const float*)d_in[27];
  const float* Wo2 = (const float*)d_in[28];
  const float* Wf  = (const float*)d_in[29];
  const float* Wh1 = (const float*)d_in[30];
  const float* Wh2 = (const float*)d_in[31];
  (void)in_sizes; (void)n_in;

  // bump allocator over workspace (ws ~256 MiB)
  char* p = (char*)d_ws;
  auto allocB = [&](size_t bytes) -> void* {
    void* r = (void*)p;
    p += (bytes + 255) & ~(size_t)255;
    return r;
  };
  auto allocF = [&](size_t nf) -> float* { return (float*)allocB(nf * 4); };
  auto allocH = [&](size_t nh) -> bf16*  { return (bf16*)allocB(nh * 2); };

  bf16*  rbf   = allocH((size_t)NE * 128);
  float* y1    = allocF((size_t)NE * 3);
  float* y2    = allocF((size_t)NE * 5);
  float* y12   = allocF((size_t)NE * 8);
  bf16*  h1    = allocH((size_t)NE * 64);
  bf16*  h2c   = allocH((size_t)6 * NE * 64);   // cached radial h2 per block (38.4 MB)
  float* s_at  = allocF((size_t)NN * 128);
  bf16*  s_atb = allocH((size_t)NN * 128);
  float* inj   = allocF((size_t)NN * 480);
  float* x     = allocF((size_t)NN * 480);
  bf16*  xnb   = allocH((size_t)NN * 480);
  bf16*  xrec  = allocH((size_t)NN * 512);   // attn-packed node record (full-wave)
  bf16*  xrec2 = allocH((size_t)NN * 256);   // attn-packed node record (lo lanes)
  bf16*  qcat  = allocH((size_t)NN * 224);
  bf16*  qv1   = allocH((size_t)NN * 192);
  bf16*  qv2   = allocH((size_t)NN * 160);
  bf16*  attb  = allocH((size_t)NN * 480);
  bf16*  ybs   = allocH((size_t)NN * 128);
  int* counts  = (int*)allocB((size_t)NN * 4);
  int* indptr  = (int*)allocB((size_t)(NN + 1) * 4);
  int* nextp   = (int*)allocB((size_t)NN * 4);
  int* order   = (int*)allocB((size_t)NE * 4);
  int* srcp    = (int*)allocB((size_t)NE * 4);
  int* norder  = (int*)allocB((size_t)NN * 4);
  int* dbins   = (int*)allocB((size_t)MAXD * 4);
  int* dboff   = (int*)allocB((size_t)MAXD * 4);
  float* spd1  = allocF((size_t)NN * 64);   // degree phase only
  float* spd2  = allocF((size_t)NN * 32);

  // lifetime aliases
  bf16*  ycat = qcat;               // q dead before FFN
  bf16*  yv1  = qv1;
  bf16*  yv2  = qv2;
  bf16*  xsb  = s_atb;              // s_atb dead after precompute

  // bf16 transposed weights
  bf16* Pd1t = allocH(64*128);
  bf16* Pd2t = allocH(32*128);
  bf16* Rd1t = allocH(64*128);
  bf16* Rd2t = allocH(64*64);
  bf16* Rd3t = allocH(320*64);
  bf16* catq = allocH((size_t)6*224*128);   // [Wq0^T | P1^T | P2^T]
  bf16* Wq1t = allocH((size_t)6*64*64);
  bf16* Wq2t = allocH((size_t)6*32*32);
  bf16* R1t  = allocH((size_t)6*64*128);
  bf16* R2t  = allocH((size_t)6*64*64);
  bf16* R3t  = allocH((size_t)6*640*64);    // PACKED-PERMUTED for attn
  bf16* Wp0t = allocH((size_t)6*128*128);
  bf16* Wp1t = allocH((size_t)6*64*64);
  bf16* Wp2t = allocH((size_t)6*32*32);
  bf16* cati = allocH((size_t)6*224*128);   // [Wi0^T | Wg^T]
  bf16* Wi1t = allocH((size_t)6*64*64);
  bf16* Wi2t = allocH((size_t)6*32*32);
  bf16* Wo0t = allocH((size_t)6*128*128);
  bf16* Wo1t = allocH((size_t)6*64*64);
  bf16* Wo2t = allocH((size_t)6*32*32);
  bf16* Wft  = allocH(512*128);
  bf16* Wh1t = allocH((size_t)512*512);

  size_t used = (size_t)(p - (char*)d_ws);
  size_t avail = (ws_size > used) ? ws_size - used : 0;
  const size_t slotH = (size_t)NE * 640 * sizeof(bf16);   // 61 MiB

  if (avail < slotH) {
    hipMemsetAsync(d_out, 0, (size_t)out_size * 4, stream);
    return;
  }
  bf16* w = (bf16*)allocB(slotH);   // single modulate-weight slot

  // readout buffers live in the w slot (dead by readout time)
  float* feat  = (float*)w;
  bf16*  featb = (bf16*)(feat + (size_t)NN*512);
  float* hb    = (float*)(featb + (size_t)NN*512);

  auto transp = [&](const float* src, bf16* dst, int R, int C, long sSrc, long sDst, int nz) {
    dim3 g((R*C + 255)/256, 1, nz);
    transp_kernel<<<g, 256, 0, stream>>>(src, dst, R, C, sSrc, sDst);
  };
  auto gemmF = [&](const bf16* A, const bf16* Bt, float* C, int M, int Nn, int K,
                   int lda, int ldc, int epi) {
    dim3 g((M + 63) / 64, (Nn + 63) / 64, 1);
    mgemm_kernel<float><<<g, 256, 0, stream>>>(A, Bt, C, M, Nn, K, lda, ldc, epi);
  };
  auto gemmH = [&](const bf16* A, const bf16* Bt, bf16* C, int M, int Nn, int K,
                   int lda, int ldc, int epi) {
    dim3 g((M + 63) / 64, (Nn + 63) / 64, 1);
    mgemm_kernel<bf16><<<g, 256, 0, stream>>>(A, Bt, C, M, Nn, K, lda, ldc, epi);
  };
  auto mkseg = [&](const bf16* A, const bf16* Bt, void* C, int M, int N, int K,
                   int lda, int ldc, int epi, int outBf16) -> GSeg {
    GSeg g; g.A = A; g.Bt = Bt; g.C = (char*)C; g.M = M; g.N = N; g.K = K;
    g.lda = lda; g.ldc = ldc; g.epi = epi; g.outBf16 = outBf16;
    g.blk0 = 0; g.nbx = (M + 63) / 64;
    return g;
  };
  auto segBlocks = [&](const GSeg& s) -> int { return s.nbx * ((s.N + 63) / 64); };
  auto launch3 = [&](GSeg a, GSeg b, GSeg c) {
    a.blk0 = 0;
    b.blk0 = segBlocks(a);
    c.blk0 = b.blk0 + segBlocks(b);
    int total = c.blk0 + segBlocks(c);
    gseg_kernel<<<total, 256, 0, stream>>>(a, b, c, c, 3);
  };
  auto launch4 = [&](GSeg a, GSeg b, GSeg c, GSeg d) {
    a.blk0 = 0;
    b.blk0 = segBlocks(a);
    c.blk0 = b.blk0 + segBlocks(b);
    d.blk0 = c.blk0 + segBlocks(c);
    int total = d.blk0 + segBlocks(d);
    gseg_kernel<<<total, 256, 0, stream>>>(a, b, c, d, 4);
  };

  // ------------ weight prep (bf16 transposed copies)
  transp(Pd1, Pd1t, 128, 64, 0, 0, 1);
  transp(Pd2, Pd2t, 128, 32, 0, 0, 1);
  transp(Rd1, Rd1t, 128, 64, 0, 0, 1);
  transp(Rd2, Rd2t, 64, 64, 0, 0, 1);
  transp(Rd3, Rd3t, 64, 320, 0, 0, 1);
  transp(Wq0, catq,           128, 128, 128*128, 224*128, 6);
  transp(P1,  catq + 128*128, 128, 64,  128*64,  224*128, 6);
  transp(P2,  catq + 192*128, 128, 32,  128*32,  224*128, 6);
  transp(Wq1, Wq1t, 64, 64, 64*64, 64*64, 6);
  transp(Wq2, Wq2t, 32, 32, 32*32, 32*32, 6);
  transp(R1,  R1t, 128, 64, 128*64, 128*64, 6);
  transp(R2,  R2t, 64, 64, 64*64, 64*64, 6);
  transp_r3_kernel<<<(NBLK*640*64 + 255)/256, 256, 0, stream>>>(R3, R3t);
  transp(Wp0, Wp0t, 128, 128, 128*128, 128*128, 6);
  transp(Wp1, Wp1t, 64, 64, 64*64, 64*64, 6);
  transp(Wp2, Wp2t, 32, 32, 32*32, 32*32, 6);
  transp(Wi0, cati,           128, 128, 128*128, 224*128, 6);
  transp(Wg,  cati + 128*128, 128, 96,  128*96,  224*128, 6);
  transp(Wi1, Wi1t, 64, 64, 64*64, 64*64, 6);
  transp(Wi2, Wi2t, 32, 32, 32*32, 32*32, 6);
  transp(Wo0, Wo0t, 128, 128, 128*128, 128*128, 6);
  transp(Wo1, Wo1t, 64, 64, 64*64, 64*64, 6);
  transp(Wo2, Wo2t, 32, 32, 32*32, 32*32, 6);
  transp(Wf,  Wft, 128, 512, 0, 0, 1);
  transp(Wh1, Wh1t, 512, 512, 0, 0, 1);

  // ------------ precompute
  hipMemsetAsync(counts, 0, NN * 4, stream);
  hipMemsetAsync(dbins, 0, MAXD * 4, stream);
  hipMemsetAsync(d_out, 0, (size_t)out_size * 4, stream);
  gather_atom_kernel<<<(NN*128 + 255)/256, 256, 0, stream>>>(atom_z, atom_table, s_at, s_atb);
  hist_kernel<<<(NE + 255)/256, 256, 0, stream>>>(edst, counts);
  scan_kernel<<<1, 1024, 0, stream>>>(counts, indptr, nextp);
  scatter_kernel<<<(NE + 255)/256, 256, 0, stream>>>(edst, nextp, order);
  edge_perm_kernel<<<NE, 128, 0, stream>>>(pos, esrc, edst, order, srcp, rbf, y1, y2, y12);
  // degree-descending node order for attn dispatch balance
  dhist_kernel<<<(NN + 255)/256, 256, 0, stream>>>(indptr, dbins);
  dscan_kernel<<<1, MAXD, 0, stream>>>(dbins, dboff);
  dplace_kernel<<<(NN + 255)/256, 256, 0, stream>>>(indptr, dboff, norder);
  gemmF(s_atb, Pd1t, spd1, NN, 64, 128, 128, 64, 0);
  gemmF(s_atb, Pd2t, spd2, NN, 32, 128, 128, 32, 0);
  // degree radial chain (uses h2c[0] as temp; refilled by pre-pass below)
  gemmH(rbf, Rd1t, h1, NE, 64, 128, 128, 64, 1);
  gemmH(h1,  Rd2t, h2c, NE, 64, 64, 64, 64, 1);
  gemmH(h2c, Rd3t, w,  NE, 320, 64, 64, 320, 0);   // wd uses UNPERMUTED Rd3t layout
  deg_inj_kernel<<<NN, 64, 0, stream>>>(indptr, srcp, w, s_at, spd1, spd2, y1, y2, inj);
  copy_kernel<<<(NN*480 + 255)/256, 256, 0, stream>>>(inj, x, NN*480);

  // radial h2 pre-pass: x-independent, compute once for all 6 blocks
  for (int i = 0; i < 6; i++) {
    gemmH(rbf, R1t + (size_t)i*64*128, h1, NE, 64, 128, 128, 64, 1);
    gemmH(h1,  R2t + (size_t)i*64*64, h2c + (size_t)i*NE*64, NE, 64, 64, 64, 64, 1);
  }

  auto run_block = [&](int i) {
    const bf16* cq  = catq + (size_t)i * 224 * 128;
    const bf16* q1t = Wq1t + (size_t)i * 64 * 64;
    const bf16* q2t = Wq2t + (size_t)i * 32 * 32;
    const bf16* r3  = R3t  + (size_t)i * 640 * 64;
    const bf16* p0t = Wp0t + (size_t)i * 128 * 128;
    const bf16* p1t = Wp1t + (size_t)i * 64 * 64;
    const bf16* p2t = Wp2t + (size_t)i * 32 * 32;
    const bf16* ci  = cati + (size_t)i * 224 * 128;
    const bf16* i1t = Wi1t + (size_t)i * 64 * 64;
    const bf16* i2t = Wi2t + (size_t)i * 32 * 32;
    const bf16* o0t = Wo0t + (size_t)i * 128 * 128;
    const bf16* o1t = Wo1t + (size_t)i * 64 * 64;
    const bf16* o2t = Wo2t + (size_t)i * 32 * 32;

    ln_kernel<<<NN, 64, 0, stream>>>(x, xnb, xrec, xrec2);
    // Q-group (qcat|qv1|qv2) + modulate-weight GEMM, all in ONE dispatch
    launch4(mkseg(xnb,          cq,  qcat, NN,   224, 128, 128, 224, 0, 1),
            mkseg(xnb + V1_OFF, q1t, qv1,  3*NN, 64,  64,  64,  64,  0, 1),
            mkseg(xnb + V2_OFF, q2t, qv2,  5*NN, 32,  32,  32,  32,  0, 1),
            mkseg(h2c + (size_t)i*NE*64, r3, w, NE, 640, 64, 64, 640, 0, 1));
    // fused online-softmax attention (packed w + y12 + xrec; defer-max)
    attn_kernel<<<NN, 64, 0, stream>>>(norder, indptr, srcp, w, xrec, xrec2, qcat, qv1, qv2, y12, attb);
    // x += eq_linear(att, Wp) (one dispatch)
    launch3(mkseg(attb,          p0t, x,          NN,   128, 128, 128, 128, 2, 0),
            mkseg(attb + V1_OFF, p1t, x + V1_OFF, 3*NN, 64,  64,  64,  64,  2, 0),
            mkseg(attb + V2_OFF, p2t, x + V2_OFF, 5*NN, 32,  32,  32,  32,  2, 0));
    // FFN
    ln_kernel<<<NN, 64, 0, stream>>>(x, xnb, nullptr, nullptr);
    launch3(mkseg(xnb,          ci,  ycat, NN,   224, 128, 128, 224, 0, 1),
            mkseg(xnb + V1_OFF, i1t, yv1,  3*NN, 64,  64,  64,  64,  0, 1),
            mkseg(xnb + V2_OFF, i2t, yv2,  5*NN, 32,  32,  32,  32,  0, 1));
    gate_kernel<<<(NN*480 + 255)/256, 256, 0, stream>>>(ycat, ybs, yv1, yv2);
    launch3(mkseg(ybs, o0t, x,          NN,   128, 128, 128, 128, 2, 0),
            mkseg(yv1, o1t, x + V1_OFF, 3*NN, 64,  64,  64,  64,  2, 0),
            mkseg(yv2, o2t, x + V2_OFF, 5*NN, 32,  32,  32,  32,  2, 0));
  };

  // ------------ DEQ unroll: z=0; twice {x = z + inj; 5 blocks}; then block 5
  for (int t = 0; t < 2; t++) {
    if (t == 1) addinj_kernel<<<(NN*480 + 255)/256, 256, 0, stream>>>(x, inj, NN*480);
    for (int i = 0; i < 5; i++) run_block(i);
  }
  run_block(5);

  // ------------ readout (feat/hb/featb live in the dead w slot)
  cvt128_kernel<<<(NN*128 + 255)/256, 256, 0, stream>>>(x, xsb);
  gemmF(xsb, Wft, feat, NN, 512, 128, 128, 512, 0);
  ln512_kernel<<<NN, 64, 0, stream>>>(feat, featb);
  gemmF(featb, Wh1t, hb, NN, 512, 512, 512, 512, 1);
  dot_seg_kernel<<<NN, 64, 0, stream>>>(hb, Wh2, bseg, (float*)d_out);
}

// Round 20
// 1747.127 us; speedup vs baseline: 1.0418x; 1.0174x over previous
//
#include <hip/hip_runtime.h>
#include <hip/hip_bf16.h>
#include <math.h>

// Problem constants
#define NN 10000      // nodes
#define NE 50000      // edges
#define NBLK 6
#define MAXD 256      // degree clamp for counting sort
// feature split: C0=128 scalars, C1=64 l1-vectors (3 comps), C2=32 l2-vectors (5 comps)
// planar layout inside a node-feature buffer of NN*480 elems:
//   S  at [0, NN*128)                 row-major N x 128
//   V1 plane m at NN*128 + m*NN*64    row-major N x 64, m=0..2
//   V2 plane m at NN*320 + m*NN*32    row-major N x 32, m=0..4
#define V1_OFF (NN*128)
#define V2_OFF (NN*320)

typedef __hip_bfloat16 bf16;
typedef __attribute__((ext_vector_type(8))) short short8;
typedef __attribute__((ext_vector_type(4))) short short4v;
typedef __attribute__((ext_vector_type(4))) float f32x4;

__device__ __forceinline__ float ldw(const float* p){ return *p; }
__device__ __forceinline__ float ldw(const bf16* p){ return __bfloat162float(*p); }
__device__ __forceinline__ void stw(float* p, float v){ *p = v; }
__device__ __forceinline__ void stw(bf16* p, float v){ *p = __float2bfloat16(v); }
__device__ __forceinline__ float b2f(short u){
  unsigned int x = ((unsigned int)(unsigned short)u) << 16;
  return __builtin_bit_cast(float, x);
}
__device__ __forceinline__ short f2b(float v){
  return __builtin_bit_cast(short, (unsigned short)(__builtin_bit_cast(unsigned int, v) >> 16 ));
}

// ---------------------------------------------------------------- MFMA GEMM
// C[M x Nn] = A[M x K] @ B; A bf16 row-major (lda); B PRE-TRANSPOSED bf16
// Bt[Nn x K] row-major (ld=K). f32 accumulate. K mult of 32.
// epi: 0=store, 1=silu, 2=accumulate into C, 3=sigmoid
// Grid is (colBlocks, rowBlocks): blockIdx.x = COLUMN tile (fastest) so
// consecutive blocks share the same A row-tile (L2-friendly A streaming).
template<typename OutT>
__global__ __launch_bounds__(256)
void mgemm_kernel(const bf16* __restrict__ A, const bf16* __restrict__ Bt,
                  OutT* __restrict__ C, int M, int Nn, int K,
                  int lda, int ldc, int epi)
{
  __shared__ __align__(16) unsigned short Ash[64][40];
  __shared__ __align__(16) unsigned short Bsh[64][40];
  int tid  = threadIdx.x;
  int wid  = tid >> 6, lane = tid & 63;
  int wr   = wid >> 1, wc = wid & 1;
  int rowBase = blockIdx.y * 64, colBase = blockIdx.x * 64;
  int fr = lane & 15;
  int fk = (lane >> 4) * 8;
  f32x4 acc[2][2] = {};
  int am = tid >> 2, ako = (tid & 3) * 8;

  for (int k0 = 0; k0 < K; k0 += 32) {
    {
      int gm = rowBase + am;
      short8 v = {0,0,0,0,0,0,0,0};
      if (gm < M) v = *reinterpret_cast<const short8*>(A + (long)gm * lda + k0 + ako);
      *reinterpret_cast<short8*>(&Ash[am][ako]) = v;
    }
    {
      int gn = colBase + am;
      short8 v = {0,0,0,0,0,0,0,0};
      if (gn < Nn) v = *reinterpret_cast<const short8*>(Bt + (long)gn * K + k0 + ako);
      *reinterpret_cast<short8*>(&Bsh[am][ako]) = v;
    }
    __syncthreads();
    short8 a0 = *reinterpret_cast<const short8*>(&Ash[wr*32 +      fr][fk]);
    short8 a1 = *reinterpret_cast<const short8*>(&Ash[wr*32 + 16 + fr][fk]);
    short8 b0 = *reinterpret_cast<const short8*>(&Bsh[wc*32 +      fr][fk]);
    short8 b1 = *reinterpret_cast<const short8*>(&Bsh[wc*32 + 16 + fr][fk]);
    acc[0][0] = __builtin_amdgcn_mfma_f32_16x16x32_bf16(a0, b0, acc[0][0], 0, 0, 0);
    acc[0][1] = __builtin_amdgcn_mfma_f32_16x16x32_bf16(a0, b1, acc[0][1], 0, 0, 0);
    acc[1][0] = __builtin_amdgcn_mfma_f32_16x16x32_bf16(a1, b0, acc[1][0], 0, 0, 0);
    acc[1][1] = __builtin_amdgcn_mfma_f32_16x16x32_bf16(a1, b1, acc[1][1], 0, 0, 0);
    __syncthreads();
  }
  int erow = (lane >> 4) * 4, ecol = lane & 15;
  #pragma unroll
  for (int tm = 0; tm < 2; tm++) {
    #pragma unroll
    for (int tn = 0; tn < 2; tn++) {
      #pragma unroll
      for (int r = 0; r < 4; r++) {
        int gm = rowBase + wr*32 + tm*16 + erow + r;
        int gn = colBase + wc*32 + tn*16 + ecol;
        if (gm < M && gn < Nn) {
          float v = acc[tm][tn][r];
          long off = (long)gm * ldc + gn;
          if (epi == 1)      v = v / (1.f + expf(-v));
          else if (epi == 2) v = v + ldw(&C[off]);
          else if (epi == 3) v = 1.f / (1.f + expf(-v));
          stw(&C[off], v);
        }
      }
    }
  }
}

// ---------------------------------------------------------------- grouped GEMM
// up to 4 independent segments in one dispatch (flattened tight grid)
// nbc = number of COLUMN blocks; consecutive blocks sweep columns first so
// each A row-tile is read once and stays in L2 across its column sweep.
struct GSeg {
  const bf16* A; const bf16* Bt; char* C;
  int M, N, K, lda, ldc, epi, outBf16, blk0, nbc;
};

__global__ __launch_bounds__(256)
void gseg_kernel(GSeg s0, GSeg s1, GSeg s2, GSeg s3, int nseg)
{
  GSeg s = s0;
  int b = blockIdx.x;
  if (nseg > 1 && b >= s1.blk0) s = s1;
  if (nseg > 2 && b >= s2.blk0) s = s2;
  if (nseg > 3 && b >= s3.blk0) s = s3;
  int rel = b - s.blk0;
  int by = rel % s.nbc, bx = rel / s.nbc;

  __shared__ __align__(16) unsigned short Ash[64][40];
  __shared__ __align__(16) unsigned short Bsh[64][40];
  int tid  = threadIdx.x;
  int wid  = tid >> 6, lane = tid & 63;
  int wr   = wid >> 1, wc = wid & 1;
  int rowBase = bx * 64, colBase = by * 64;
  int fr = lane & 15;
  int fk = (lane >> 4) * 8;
  f32x4 acc[2][2] = {};
  int am = tid >> 2, ako = (tid & 3) * 8;

  for (int k0 = 0; k0 < s.K; k0 += 32) {
    {
      int gm = rowBase + am;
      short8 v = {0,0,0,0,0,0,0,0};
      if (gm < s.M) v = *reinterpret_cast<const short8*>(s.A + (long)gm * s.lda + k0 + ako);
      *reinterpret_cast<short8*>(&Ash[am][ako]) = v;
    }
    {
      int gn = colBase + am;
      short8 v = {0,0,0,0,0,0,0,0};
      if (gn < s.N) v = *reinterpret_cast<const short8*>(s.Bt + (long)gn * s.K + k0 + ako);
      *reinterpret_cast<short8*>(&Bsh[am][ako]) = v;
    }
    __syncthreads();
    short8 a0 = *reinterpret_cast<const short8*>(&Ash[wr*32 +      fr][fk]);
    short8 a1 = *reinterpret_cast<const short8*>(&Ash[wr*32 + 16 + fr][fk]);
    short8 b0 = *reinterpret_cast<const short8*>(&Bsh[wc*32 +      fr][fk]);
    short8 b1 = *reinterpret_cast<const short8*>(&Bsh[wc*32 + 16 + fr][fk]);
    acc[0][0] = __builtin_amdgcn_mfma_f32_16x16x32_bf16(a0, b0, acc[0][0], 0, 0, 0);
    acc[0][1] = __builtin_amdgcn_mfma_f32_16x16x32_bf16(a0, b1, acc[0][1], 0, 0, 0);
    acc[1][0] = __builtin_amdgcn_mfma_f32_16x16x32_bf16(a1, b0, acc[1][0], 0, 0, 0);
    acc[1][1] = __builtin_amdgcn_mfma_f32_16x16x32_bf16(a1, b1, acc[1][1], 0, 0, 0);
    __syncthreads();
  }
  int erow = (lane >> 4) * 4, ecol = lane & 15;
  #pragma unroll
  for (int tm = 0; tm < 2; tm++) {
    #pragma unroll
    for (int tn = 0; tn < 2; tn++) {
      #pragma unroll
      for (int r = 0; r < 4; r++) {
        int gm = rowBase + wr*32 + tm*16 + erow + r;
        int gn = colBase + wc*32 + tn*16 + ecol;
        if (gm < s.M && gn < s.N) {
          float v = acc[tm][tn][r];
          long off = (long)gm * s.ldc + gn;
          if (s.epi == 1)      v = v / (1.f + expf(-v));
          else if (s.epi == 2) v = v + (s.outBf16 ? ldw((const bf16*)s.C + off)
                                                 : ldw((const float*)s.C + off));
          else if (s.epi == 3) v = 1.f / (1.f + expf(-v));
          if (s.outBf16) stw((bf16*)s.C + off, v);
          else           stw((float*)s.C + off, v);
        }
      }
    }
  }
}

// ---------------------------------------------------------------- transpose+cvt
__global__ void transp_kernel(const float* __restrict__ src, bf16* __restrict__ dst,
                              int R, int C, long sSrc, long sDst)
{
  src += (long)blockIdx.z * sSrc;
  dst += (long)blockIdx.z * sDst;
  int idx = blockIdx.x * 256 + threadIdx.x;
  if (idx < R * C) {
    int r = idx / C, c = idx - r * C;
    dst[(long)c * R + r] = __float2bfloat16(src[idx]);
  }
}

// R3 transpose with attn-packed column permutation:
// new col layout: [t*8+j] j=0..7 -> old cols {t,64+t,128+t,192+t,320+t,384+t,448+t,512+t}
//                 [512+t32*4+j] j=0..3 -> old cols {256+t32,288+t32,576+t32,608+t32}
__global__ void transp_r3_kernel(const float* __restrict__ src, bf16* __restrict__ dst)
{
  int idx = blockIdx.x * 256 + threadIdx.x;     // over NBLK*640*64
  if (idx >= NBLK * 640 * 64) return;
  int blk  = idx / (640 * 64);
  int rem  = idx - blk * 640 * 64;
  int newc = rem >> 6;          // dst row (0..639)
  int k    = rem & 63;          // dst col (K)
  int oldc;
  if (newc < 512) {
    int t = newc >> 3, j = newc & 7;
    const int base[8] = {0, 64, 128, 192, 320, 384, 448, 512};
    oldc = base[j] + t;
  } else {
    int q = newc - 512;
    int t32 = q >> 2, j = q & 3;
    const int base2[4] = {256, 288, 576, 608};
    oldc = base2[j] + t32;
  }
  dst[idx] = __float2bfloat16(src[(size_t)blk * 64 * 640 + (size_t)k * 640 + oldc]);
}

// ---------------------------------------------------------------- small kernels
__global__ void gather_atom_kernel(const int* __restrict__ z, const float* __restrict__ tab,
                                   float* __restrict__ s_atom, bf16* __restrict__ s_atom_bf)
{
  int idx = blockIdx.x * 256 + threadIdx.x;
  if (idx < NN * 128) {
    int n = idx >> 7, c = idx & 127;
    float v = tab[z[n] * 128 + c];
    s_atom[idx] = v;
    s_atom_bf[idx] = __float2bfloat16(v);
  }
}

__global__ void hist_kernel(const int* __restrict__ dst, int* __restrict__ counts)
{
  int e = blockIdx.x * 256 + threadIdx.x;
  if (e < NE) atomicAdd(&counts[dst[e]], 1);
}

__global__ __launch_bounds__(1024)
void scan_kernel(const int* __restrict__ counts, int* __restrict__ indptr,
                 int* __restrict__ nextp)
{
  __shared__ int totals[1024];
  const int PER = (NN + 1023) / 1024;   // 10
  int tid = threadIdx.x;
  int base = tid * PER;
  int local[PER];
  int s = 0;
  #pragma unroll
  for (int i = 0; i < PER; i++) {
    int idx = base + i;
    int c = (idx < NN) ? counts[idx] : 0;
    local[i] = s; s += c;
  }
  totals[tid] = s;
  __syncthreads();
  for (int off = 1; off < 1024; off <<= 1) {
    int v = (tid >= off) ? totals[tid - off] : 0;
    __syncthreads();
    totals[tid] += v;
    __syncthreads();
  }
  int prefix = (tid > 0) ? totals[tid - 1] : 0;
  #pragma unroll
  for (int i = 0; i < PER; i++) {
    int idx = base + i;
    if (idx < NN) { indptr[idx] = prefix + local[i]; nextp[idx] = prefix + local[i]; }
  }
  if (tid == 1023) indptr[NN] = totals[1023];
}

__global__ void scatter_kernel(const int* __restrict__ dst, int* __restrict__ nextp,
                               int* __restrict__ order)
{
  int e = blockIdx.x * 256 + threadIdx.x;
  if (e < NE) {
    int p = atomicAdd(&nextp[dst[e]], 1);
    order[p] = e;
  }
}

// ---- degree-descending node order (counting sort; output-order independent)
__global__ void dhist_kernel(const int* __restrict__ indptr, int* __restrict__ bins)
{
  int n = blockIdx.x * 256 + threadIdx.x;
  if (n < NN) {
    int d = indptr[n+1] - indptr[n]; if (d > MAXD-1) d = MAXD-1;
    atomicAdd(&bins[MAXD-1-d], 1);
  }
}
__global__ __launch_bounds__(256)
void dscan_kernel(const int* __restrict__ bins, int* __restrict__ boff)
{
  __shared__ int tmp[MAXD];
  int t = threadIdx.x;
  tmp[t] = bins[t];
  __syncthreads();
  for (int off = 1; off < MAXD; off <<= 1) {
    int v = (t >= off) ? tmp[t-off] : 0;
    __syncthreads();
    tmp[t] += v;
    __syncthreads();
  }
  boff[t] = tmp[t] - bins[t];
}
__global__ void dplace_kernel(const int* __restrict__ indptr, int* __restrict__ boff,
                              int* __restrict__ norder)
{
  int n = blockIdx.x * 256 + threadIdx.x;
  if (n < NN) {
    int d = indptr[n+1] - indptr[n]; if (d > MAXD-1) d = MAXD-1;
    int pos = atomicAdd(&boff[MAXD-1-d], 1);
    norder[pos] = n;
  }
}

// edge geometry, stored in CSR-permuted order (position idx = sorted-by-dst)
// y12: packed [y1[3] | y2[5]] per edge for attn vector loads
__global__ __launch_bounds__(128)
void edge_perm_kernel(const float* __restrict__ pos, const int* __restrict__ esrc,
                      const int* __restrict__ edst, const int* __restrict__ order,
                      int* __restrict__ srcp, bf16* __restrict__ rbf,
                      float* __restrict__ y1, float* __restrict__ y2,
                      float* __restrict__ y12)
{
  int idx = blockIdx.x, t = threadIdx.x;
  int e = order[idx];
  int s = esrc[e], d = edst[e];
  float vx = pos[d*3+0] - pos[s*3+0];
  float vy = pos[d*3+1] - pos[s*3+1];
  float vz = pos[d*3+2] - pos[s*3+2];
  float r = sqrtf(vx*vx + vy*vy + vz*vz + 1e-12f);
  float mu = t * (5.0f / 127.0f);
  const float inv_sig = 128.0f / 5.0f;
  float zq = (r - mu) * inv_sig;
  rbf[(long)idx * 128 + t] = __float2bfloat16(expf(-0.5f * zq * zq));
  if (t == 0) {
    srcp[idx] = s;
    float inv = 1.f / r;
    float ux = vx*inv, uy = vy*inv, uz = vz*inv;
    const float s3  = 1.7320508075688772f;   // sqrt(3)
    const float s15 = 3.872983346207417f;    // sqrt(15)
    float a0 = s3*ux, a1 = s3*uy, a2 = s3*uz;
    float b0 = s15*ux*uy;
    float b1 = s15*uy*uz;
    float b2 = 1.118033988749895f * (3.f*uz*uz - 1.f);   // sqrt(1.25)
    float b3 = s15*ux*uz;
    float b4 = 1.9364916731037085f * (ux*ux - uy*uy);    // sqrt(3.75)
    y1[idx*3+0] = a0; y1[idx*3+1] = a1; y1[idx*3+2] = a2;
    y2[idx*5+0] = b0; y2[idx*5+1] = b1; y2[idx*5+2] = b2;
    y2[idx*5+3] = b3; y2[idx*5+4] = b4;
    y12[(size_t)idx*8+0] = a0; y12[(size_t)idx*8+1] = a1;
    y12[(size_t)idx*8+2] = a2; y12[(size_t)idx*8+3] = b0;
    y12[(size_t)idx*8+4] = b1; y12[(size_t)idx*8+5] = b2;
    y12[(size_t)idx*8+6] = b3; y12[(size_t)idx*8+7] = b4;
  }
}

__global__ void copy_kernel(const float* __restrict__ a, float* __restrict__ b, int n)
{
  int i = blockIdx.x * 256 + threadIdx.x;
  if (i < n) b[i] = a[i];
}

__global__ void addinj_kernel(float* __restrict__ x, const float* __restrict__ inj, int n)
{
  int i = blockIdx.x * 256 + threadIdx.x;
  if (i < n) x[i] += inj[i];
}

__global__ void cvt128_kernel(const float* __restrict__ a, bf16* __restrict__ b)
{
  int i = blockIdx.x * 256 + threadIdx.x;
  if (i < NN * 128) b[i] = __float2bfloat16(a[i]);
}

// ---------------------------------------------------------------- equivariant LN
// Outputs planar bf16 (GEMM A-operand) and, when xrec != nullptr, the
// attn-packed node records:
//   xrec [n][64][8]: slots {s0, s1, v1_0, v1_1, v1_2} per lane t
//   xrec2[n][32][8]: slots {v2_0..v2_4}            per lane t32 (lo lanes)
__global__ __launch_bounds__(64)
void ln_kernel(const float* __restrict__ x, bf16* __restrict__ ob,
               bf16* __restrict__ xrec, bf16* __restrict__ xrec2)
{
  int n = blockIdx.x, t = threadIdx.x;
  bool lo = t < 32;
  int t32 = t & 31;
  float s0 = x[n*128 + t], s1 = x[n*128 + 64 + t];
  float v1v[3], v2v[5];
  #pragma unroll
  for (int m = 0; m < 3; m++) v1v[m] = x[V1_OFF + m*NN*64 + n*64 + t];
  #pragma unroll
  for (int m = 0; m < 5; m++) v2v[m] = lo ? x[V2_OFF + m*NN*32 + n*32 + t32] : 0.f;
  float ssum = s0 + s1, ssq = s0*s0 + s1*s1;
  float q1 = v1v[0]*v1v[0] + v1v[1]*v1v[1] + v1v[2]*v1v[2];
  float q2 = 0.f;
  #pragma unroll
  for (int m = 0; m < 5; m++) q2 += v2v[m]*v2v[m];
  #pragma unroll
  for (int d = 32; d >= 1; d >>= 1) {
    ssum += __shfl_xor(ssum, d);
    ssq  += __shfl_xor(ssq, d);
    q1   += __shfl_xor(q1, d);
    q2   += __shfl_xor(q2, d);
  }
  float mu  = ssum * (1.f/128.f);
  float var = fmaxf(ssq * (1.f/128.f) - mu*mu, 0.f);
  float is  = rsqrtf(var + 1e-5f);
  float i1  = rsqrtf(q1 * (1.f/64.f) + 1e-5f);
  float i2  = rsqrtf(q2 * (1.f/32.f) + 1e-5f);
  float os0 = (s0 - mu) * is, os1 = (s1 - mu) * is;
  float ov1[3], ov2[5];
  #pragma unroll
  for (int m = 0; m < 3; m++) ov1[m] = v1v[m] * i1;
  #pragma unroll
  for (int m = 0; m < 5; m++) ov2[m] = v2v[m] * i2;
  ob[n*128 + t]      = __float2bfloat16(os0);
  ob[n*128 + 64 + t] = __float2bfloat16(os1);
  #pragma unroll
  for (int m = 0; m < 3; m++)
    ob[V1_OFF + m*NN*64 + n*64 + t] = __float2bfloat16(ov1[m]);
  if (lo) {
    #pragma unroll
    for (int m = 0; m < 5; m++)
      ob[V2_OFF + m*NN*32 + n*32 + t32] = __float2bfloat16(ov2[m]);
  }
  if (xrec) {
    short8 r;
    r[0] = f2b(os0); r[1] = f2b(os1);
    r[2] = f2b(ov1[0]); r[3] = f2b(ov1[1]); r[4] = f2b(ov1[2]);
    r[5] = 0; r[6] = 0; r[7] = 0;
    *reinterpret_cast<short8*>(xrec + (size_t)n*512 + t*8) = r;
    if (lo) {
      short8 r2;
      r2[0] = f2b(ov2[0]); r2[1] = f2b(ov2[1]); r2[2] = f2b(ov2[2]);
      r2[3] = f2b(ov2[3]); r2[4] = f2b(ov2[4]);
      r2[5] = 0; r2[6] = 0; r2[7] = 0;
      *reinterpret_cast<short8*>(xrec2 + (size_t)n*256 + t32*8) = r2;
    }
  }
}

// ---------------------------------------------------------------- degree embedding
__global__ __launch_bounds__(64)
void deg_inj_kernel(const int* __restrict__ indptr, const int* __restrict__ srcp,
                    const bf16* __restrict__ wd,
                    const float* __restrict__ s_atom, const float* __restrict__ spd1,
                    const float* __restrict__ spd2, const float* __restrict__ y1,
                    const float* __restrict__ y2, float* __restrict__ inj)
{
  int n = blockIdx.x, t = threadIdx.x;
  bool lo = t < 32;
  int t32 = t & 31;
  float acc0 = 0, acc1 = 0, a1[3] = {0,0,0}, a2[5] = {0,0,0,0,0};
  int beg = indptr[n], end = indptr[n+1];
  for (int idx = beg; idx < end; ++idx) {
    int s = srcp[idx];
    const bf16* we = wd + (size_t)idx * 320;
    acc0 += s_atom[s*128 + t]      * ldw(&we[t]);
    acc1 += s_atom[s*128 + 64 + t] * ldw(&we[64 + t]);
    float sp1e = spd1[s*64 + t];
    float w2k = ldw(&we[192 + t]);
    #pragma unroll
    for (int m = 0; m < 3; m++) a1[m] += sp1e * y1[idx*3+m] * w2k;
    float sp2e = lo ? spd2[s*32 + t32] : 0.f;
    float w4k  = lo ? ldw(&we[288 + t32]) : 0.f;
    #pragma unroll
    for (int m = 0; m < 5; m++) a2[m] += sp2e * y2[idx*5+m] * w4k;
  }
  const float inv = 0.25f;  // 1/sqrt(AVG_DEGREE=16)
  inj[n*128 + t]      = s_atom[n*128 + t]      + acc0 * inv;
  inj[n*128 + 64 + t] = s_atom[n*128 + 64 + t] + acc1 * inv;
  #pragma unroll
  for (int m = 0; m < 3; m++) inj[V1_OFF + m*NN*64 + n*64 + t] = a1[m] * inv;
  if (lo) {
    #pragma unroll
    for (int m = 0; m < 5; m++) inj[V2_OFF + m*NN*32 + n*32 + t32] = a2[m] * inv;
  }
}

// ---------------------------------------------------------------- fused attention
// R17-best + 11-shuffle head reduction (same summation tree as the 24-shuffle
// butterfly per head -> bit-identical results, ~26 fewer VALU ops/edge).
__global__ __launch_bounds__(64)
void attn_kernel(const int* __restrict__ norder,
                 const int* __restrict__ indptr, const int* __restrict__ srcp,
                 const bf16* __restrict__ w,
                 const bf16* __restrict__ xrec, const bf16* __restrict__ xrec2,
                 const bf16* __restrict__ qcat,
                 const bf16* __restrict__ qv1b, const bf16* __restrict__ qv2b,
                 const float* __restrict__ y12,
                 bf16* __restrict__ att)
{
  int n = norder[blockIdx.x];
  int t = threadIdx.x;
  bool lo = t < 32;
  int t32 = t & 31;
  const float qscl = 0.09128709291752769f;   // 1/sqrt(HD=120)
  float qs0 = ldw(&qcat[n*224 + t]) * qscl, qs1 = ldw(&qcat[n*224 + 64 + t]) * qscl;
  float qv1[3], qv2[5];
  #pragma unroll
  for (int m = 0; m < 3; m++) qv1[m] = ldw(&qv1b[m*NN*64 + n*64 + t]) * qscl;
  #pragma unroll
  for (int m = 0; m < 5; m++) qv2[m] = lo ? ldw(&qv2b[m*NN*32 + n*32 + t32]) * qscl : 0.f;
  const int h_s0 = t >> 5, h_s1 = 2 + (t >> 5), h_v1 = t >> 4, h_v2 = t32 >> 3;
  const int sel1 = t & 1, sel2 = t & 2;
  const int bcast = t & ~3;
  float m_run[4] = {-1e30f, -1e30f, -1e30f, -1e30f};
  float d_run[4] = {0, 0, 0, 0};
  float as0 = 0, as1 = 0, av1[3] = {0,0,0}, av2[5] = {0,0,0,0,0};
  int beg = indptr[n], end = indptr[n+1];
  for (int idx = beg; idx < end; ++idx) {
    int s = srcp[idx];
    const bf16* we = w + (size_t)idx * 640;
    // packed weights: one 16B load (full-wave) + one 8B load (lo lanes)
    short8 w8 = *reinterpret_cast<const short8*>(we + t*8);
    float kw0 = b2f(w8[0]), kw1 = b2f(w8[1]), w1k = b2f(w8[2]), w2k = b2f(w8[3]);
    float vw0 = b2f(w8[4]), vw1 = b2f(w8[5]), w1v = b2f(w8[6]), w2v = b2f(w8[7]);
    float w3k = 0, w4k = 0, w3v = 0, w4v = 0;
    if (lo) {
      short4v l4 = *reinterpret_cast<const short4v*>(we + 512 + t32*4);
      w3k = b2f(l4[0]); w4k = b2f(l4[1]); w3v = b2f(l4[2]); w4v = b2f(l4[3]);
    }
    // packed node record: one 16B load replaces 5 gathers
    short8 xr = *reinterpret_cast<const short8*>(xrec + (size_t)s*512 + t*8);
    float sE0 = b2f(xr[0]), sE1 = b2f(xr[1]);
    float v1E[3] = {b2f(xr[2]), b2f(xr[3]), b2f(xr[4])};
    float v2E[5] = {0,0,0,0,0};
    if (lo) {
      short8 xr2 = *reinterpret_cast<const short8*>(xrec2 + (size_t)s*256 + t32*8);
      v2E[0] = b2f(xr2[0]); v2E[1] = b2f(xr2[1]); v2E[2] = b2f(xr2[2]);
      v2E[3] = b2f(xr2[3]); v2E[4] = b2f(xr2[4]);
    }
    float sp1e = ldw(&qcat[s*224 + 128 + t]);
    float sp2e = lo ? ldw(&qcat[s*224 + 192 + t32]) : 0.f;
    // packed spherical harmonics: 2 vector loads replace 8 scalar loads
    float4 ya = *reinterpret_cast<const float4*>(&y12[(size_t)idx*8]);
    float Y1[3] = {ya.x, ya.y, ya.z};
    float Y2[5] = {0,0,0,0,0};
    if (lo) {
      float4 yb = *reinterpret_cast<const float4*>(&y12[(size_t)idx*8 + 4]);
      Y2[0] = ya.w; Y2[1] = yb.x; Y2[2] = yb.y; Y2[3] = yb.z; Y2[4] = yb.w;
    }
    // ---- logits
    float part[4] = {0,0,0,0};
    part[h_s0] += qs0 * (sE0 * kw0);
    part[h_s1] += qs1 * (sE1 * kw1);
    #pragma unroll
    for (int m = 0; m < 3; m++) part[h_v1] += qv1[m] * (v1E[m]*w1k + sp1e*Y1[m]*w2k);
    #pragma unroll
    for (int m = 0; m < 5; m++) part[h_v2] += qv2[m] * (v2E[m]*w3k + sp2e*Y2[m]*w4k);
    // ---- 4-head reduce: fold (3 shfl) + butterfly (4 shfl) + broadcast (4 shfl)
    // Same per-head summation tree as 4x full butterflies -> bit-identical.
    {
      float fx = sel1 ? part[1] : part[0];
      float fy = sel1 ? part[0] : part[1];
      fx += __shfl_xor(fy, 1);
      float fz = sel1 ? part[3] : part[2];
      float fw = sel1 ? part[2] : part[3];
      fz += __shfl_xor(fw, 1);
      float u  = sel2 ? fz : fx;
      float v  = sel2 ? fx : fz;
      u += __shfl_xor(v, 2);
      #pragma unroll
      for (int d = 4; d < 64; d <<= 1) u += __shfl_xor(u, d);
      part[0] = __shfl(u, bcast + 0);
      part[1] = __shfl(u, bcast + 1);
      part[2] = __shfl(u, bcast + 2);
      part[3] = __shfl(u, bcast + 3);
    }
    // ---- defer-max: rescale only when a logit exceeds running max + 8
    if (part[0] > m_run[0] + 8.f || part[1] > m_run[1] + 8.f ||
        part[2] > m_run[2] + 8.f || part[3] > m_run[3] + 8.f) {
      float scl[4];
      #pragma unroll
      for (int h = 0; h < 4; h++) {
        float nm = fmaxf(m_run[h], part[h]);
        scl[h] = __expf(m_run[h] - nm);
        m_run[h] = nm;
        d_run[h] *= scl[h];
      }
      as0 *= scl[h_s0]; as1 *= scl[h_s1];
      #pragma unroll
      for (int m = 0; m < 3; m++) av1[m] *= scl[h_v1];
      #pragma unroll
      for (int m = 0; m < 5; m++) av2[m] *= scl[h_v2];
    }
    float pp[4];
    #pragma unroll
    for (int h = 0; h < 4; h++) { pp[h] = __expf(part[h] - m_run[h]); d_run[h] += pp[h]; }
    // ---- accumulate v
    as0 += pp[h_s0] * (sE0 * vw0);
    as1 += pp[h_s1] * (sE1 * vw1);
    #pragma unroll
    for (int m = 0; m < 3; m++)
      av1[m] += pp[h_v1] * (v1E[m]*w1v + sp1e*Y1[m]*w2v);
    #pragma unroll
    for (int m = 0; m < 5; m++)
      av2[m] += pp[h_v2] * (v2E[m]*w3v + sp2e*Y2[m]*w4v);
  }
  float r0 = 1.f / (d_run[h_s0] + 1e-9f);
  float r1 = 1.f / (d_run[h_s1] + 1e-9f);
  att[n*128 + t]      = __float2bfloat16(as0 * r0);
  att[n*128 + 64 + t] = __float2bfloat16(as1 * r1);
  float rv1 = 1.f / (d_run[h_v1] + 1e-9f);
  #pragma unroll
  for (int m = 0; m < 3; m++)
    att[V1_OFF + m*NN*64 + n*64 + t] = __float2bfloat16(av1[m] * rv1);
  if (lo) {
    float rv2 = 1.f / (d_run[h_v2] + 1e-9f);
    #pragma unroll
    for (int m = 0; m < 5; m++)
      att[V2_OFF + m*NN*32 + n*32 + t32] = __float2bfloat16(av2[m] * rv2);
  }
}

// ---------------------------------------------------------------- gating
// ycat = [ys(128) | g_pre(96)] bf16, ld 224. ybs = silu(ys) bf16; yv1/yv2 *= sigmoid(g).
__global__ void gate_kernel(const bf16* __restrict__ ycat, bf16* __restrict__ ybs,
                            bf16* __restrict__ yv1, bf16* __restrict__ yv2)
{
  int idx = blockIdx.x * 256 + threadIdx.x;
  if (idx >= NN * 480) return;
  if (idx < NN * 128) {
    int n = idx >> 7, c = idx & 127;
    float v = ldw(&ycat[n*224 + c]);
    ybs[idx] = __float2bfloat16(v / (1.f + expf(-v)));
  } else if (idx < NN * 320) {
    int rel = idx - NN * 128;
    int n = (rel % (NN * 64)) / 64;
    int c = rel % 64;
    float g = ldw(&ycat[n*224 + 128 + c]);
    g = 1.f / (1.f + expf(-g));
    yv1[rel] = __float2bfloat16(__bfloat162float(yv1[rel]) * g);
  } else {
    int rel = idx - NN * 320;
    int n = (rel % (NN * 32)) / 32;
    int c = rel % 32;
    float g = ldw(&ycat[n*224 + 192 + c]);
    g = 1.f / (1.f + expf(-g));
    yv2[rel] = __float2bfloat16(__bfloat162float(yv2[rel]) * g);
  }
}

// ---------------------------------------------------------------- readout
__global__ __launch_bounds__(64)
void ln512_kernel(float* __restrict__ f, bf16* __restrict__ fb)
{
  int n = blockIdx.x, t = threadIdx.x;
  float v[8];
  float s = 0, sq = 0;
  #pragma unroll
  for (int i = 0; i < 8; i++) {
    v[i] = f[(long)n*512 + i*64 + t];
    s += v[i]; sq += v[i]*v[i];
  }
  #pragma unroll
  for (int d = 32; d >= 1; d >>= 1) { s += __shfl_xor(s, d); sq += __shfl_xor(sq, d); }
  float mu  = s * (1.f/512.f);
  float var = fmaxf(sq * (1.f/512.f) - mu*mu, 0.f);
  float inv = rsqrtf(var + 1e-5f);
  #pragma unroll
  for (int i = 0; i < 8; i++) {
    float o = (v[i] - mu) * inv;
    fb[(long)n*512 + i*64 + t] = __float2bfloat16(o);
  }
}

__global__ __launch_bounds__(64)
void dot_seg_kernel(const float* __restrict__ h, const float* __restrict__ w2,
                    const int* __restrict__ bseg, float* __restrict__ out)
{
  int n = blockIdx.x, t = threadIdx.x;
  float acc = 0;
  #pragma unroll
  for (int i = 0; i < 8; i++) {
    int j = i*64 + t;
    acc += h[(long)n*512 + j] * w2[j];
  }
  #pragma unroll
  for (int d = 32; d >= 1; d >>= 1) acc += __shfl_xor(acc, d);
  if (t == 0) atomicAdd(&out[bseg[n]], acc * 0.21821789023599236f); // 1/sqrt(21)
}

// ---------------------------------------------------------------- host
extern "C" void kernel_launch(void* const* d_in, const int* in_sizes, int n_in,
                              void* d_out, int out_size, void* d_ws, size_t ws_size,
                              hipStream_t stream)
{
  const float* pos        = (const float*)d_in[0];
  const int*   atom_z     = (const int*)  d_in[1];
  const int*   esrc       = (const int*)  d_in[2];
  const int*   edst       = (const int*)  d_in[3];
  const int*   bseg       = (const int*)  d_in[4];
  const float* atom_table = (const float*)d_in[5];
  const float* Pd1 = (const float*)d_in[6];
  const float* Pd2 = (const float*)d_in[7];
  const float* Rd1 = (const float*)d_in[8];
  const float* Rd2 = (const float*)d_in[9];
  const float* Rd3 = (const float*)d_in[10];
  const float* Wq0 = (const float*)d_in[11];
  const float* Wq1 = (const float*)d_in[12];
  const float* Wq2 = (const float*)d_in[13];
  const float* P1  = (const float*)d_in[14];
  const float* P2  = (const float*)d_in[15];
  const float* R1  = (const float*)d_in[16];
  const float* R2  = (const float*)d_in[17];
  const float* R3  = (const float*)d_in[18];
  const float* Wp0 = (const float*)d_in[19];
  const float* Wp1 = (const float*)d_in[20];
  const float* Wp2 = (const float*)d_in[21];
  const float* Wg  = (const float*)d_in[22];
  const float* Wi0 = (const float*)d_in[23];
  const float* Wi1 = (const float*)d_in[24];
  const float* Wi2 = (const float*)d_in[25];
  const float* Wo0 = (const float*)d_in[26];
  const float* Wo1 = (const float*)d_in[27];
  const float* Wo2 = (const float*)d_in[28];
  const float* Wf  = (const float*)d_in[29];
  const float* Wh1 = (const float*)d_in[30];
  const float* Wh2 = (const float*)d_in[31];
  (void)in_sizes; (void)n_in;

  // bump allocator over workspace (ws ~256 MiB)
  char* p = (char*)d_ws;
  auto allocB = [&](size_t bytes) -> void* {
    void* r = (void*)p;
    p += (bytes + 255) & ~(size_t)255;
    return r;
  };
  auto allocF = [&](size_t nf) -> float* { return (float*)allocB(nf * 4); };
  auto allocH = [&](size_t nh) -> bf16*  { return (bf16*)allocB(nh * 2); };

  bf16*  rbf   = allocH((size_t)NE * 128);
  float* y1    = allocF((size_t)NE * 3);
  float* y2    = allocF((size_t)NE * 5);
  float* y12   = allocF((size_t)NE * 8);
  bf16*  h1    = allocH((size_t)NE * 64);
  bf16*  h2c   = allocH((size_t)6 * NE * 64);   // cached radial h2 per block (38.4 MB)
  float* s_at  = allocF((size_t)NN * 128);
  bf16*  s_atb = allocH((size_t)NN * 128);
  float* inj   = allocF((size_t)NN * 480);
  float* x     = allocF((size_t)NN * 480);
  bf16*  xnb   = allocH((size_t)NN * 480);
  bf16*  xrec  = allocH((size_t)NN * 512);   // attn-packed node record (full-wave)
  bf16*  xrec2 = allocH((size_t)NN * 256);   // attn-packed node record (lo lanes)
  bf16*  qcat  = allocH((size_t)NN * 224);
  bf16*  qv1   = allocH((size_t)NN * 192);
  bf16*  qv2   = allocH((size_t)NN * 160);
  bf16*  attb  = allocH((size_t)NN * 480);
  bf16*  ybs   = allocH((size_t)NN * 128);
  int* counts  = (int*)allocB((size_t)NN * 4);
  int* indptr  = (int*)allocB((size_t)(NN + 1) * 4);
  int* nextp   = (int*)allocB((size_t)NN * 4);
  int* order   = (int*)allocB((size_t)NE * 4);
  int* srcp    = (int*)allocB((size_t)NE * 4);
  int* norder  = (int*)allocB((size_t)NN * 4);
  int* dbins   = (int*)allocB((size_t)MAXD * 4);
  int* dboff   = (int*)allocB((size_t)MAXD * 4);
  float* spd1  = allocF((size_t)NN * 64);   // degree phase only
  float* spd2  = allocF((size_t)NN * 32);

  // lifetime aliases
  bf16*  ycat = qcat;               // q dead before FFN
  bf16*  yv1  = qv1;
  bf16*  yv2  = qv2;
  bf16*  xsb  = s_atb;              // s_atb dead after precompute

  // bf16 transposed weights
  bf16* Pd1t = allocH(64*128);
  bf16* Pd2t = allocH(32*128);
  bf16* Rd1t = allocH(64*128);
  bf16* Rd2t = allocH(64*64);
  bf16* Rd3t = allocH(320*64);
  bf16* catq = allocH((size_t)6*224*128);   // [Wq0^T | P1^T | P2^T]
  bf16* Wq1t = allocH((size_t)6*64*64);
  bf16* Wq2t = allocH((size_t)6*32*32);
  bf16* R1t  = allocH((size_t)6*64*128);
  bf16* R2t  = allocH((size_t)6*64*64);
  bf16* R3t  = allocH((size_t)6*640*64);    // PACKED-PERMUTED for attn
  bf16* Wp0t = allocH((size_t)6*128*128);
  bf16* Wp1t = allocH((size_t)6*64*64);
  bf16* Wp2t = allocH((size_t)6*32*32);
  bf16* cati = allocH((size_t)6*224*128);   // [Wi0^T | Wg^T]
  bf16* Wi1t = allocH((size_t)6*64*64);
  bf16* Wi2t = allocH((size_t)6*32*32);
  bf16* Wo0t = allocH((size_t)6*128*128);
  bf16* Wo1t = allocH((size_t)6*64*64);
  bf16* Wo2t = allocH((size_t)6*32*32);
  bf16* Wft  = allocH(512*128);
  bf16* Wh1t = allocH((size_t)512*512);

  size_t used = (size_t)(p - (char*)d_ws);
  size_t avail = (ws_size > used) ? ws_size - used : 0;
  const size_t slotH = (size_t)NE * 640 * sizeof(bf16);   // 61 MiB

  if (avail < slotH) {
    hipMemsetAsync(d_out, 0, (size_t)out_size * 4, stream);
    return;
  }
  bf16* w = (bf16*)allocB(slotH);   // single modulate-weight slot

  // readout buffers live in the w slot (dead by readout time)
  float* feat  = (float*)w;
  bf16*  featb = (bf16*)(feat + (size_t)NN*512);
  float* hb    = (float*)(featb + (size_t)NN*512);

  auto transp = [&](const float* src, bf16* dst, int R, int C, long sSrc, long sDst, int nz) {
    dim3 g((R*C + 255)/256, 1, nz);
    transp_kernel<<<g, 256, 0, stream>>>(src, dst, R, C, sSrc, sDst);
  };
  auto gemmF = [&](const bf16* A, const bf16* Bt, float* C, int M, int Nn, int K,
                   int lda, int ldc, int epi) {
    dim3 g((Nn + 63) / 64, (M + 63) / 64, 1);   // col-fastest for A-tile L2 reuse
    mgemm_kernel<float><<<g, 256, 0, stream>>>(A, Bt, C, M, Nn, K, lda, ldc, epi);
  };
  auto gemmH = [&](const bf16* A, const bf16* Bt, bf16* C, int M, int Nn, int K,
                   int lda, int ldc, int epi) {
    dim3 g((Nn + 63) / 64, (M + 63) / 64, 1);
    mgemm_kernel<bf16><<<g, 256, 0, stream>>>(A, Bt, C, M, Nn, K, lda, ldc, epi);
  };
  auto mkseg = [&](const bf16* A, const bf16* Bt, void* C, int M, int N, int K,
                   int lda, int ldc, int epi, int outBf16) -> GSeg {
    GSeg g; g.A = A; g.Bt = Bt; g.C = (char*)C; g.M = M; g.N = N; g.K = K;
    g.lda = lda; g.ldc = ldc; g.epi = epi; g.outBf16 = outBf16;
    g.blk0 = 0; g.nbc = (N + 63) / 64;          // column blocks (fastest)
    return g;
  };
  auto segBlocks = [&](const GSeg& s) -> int { return s.nbc * ((s.M + 63) / 64); };
  auto launch3 = [&](GSeg a, GSeg b, GSeg c) {
    a.blk0 = 0;
    b.blk0 = segBlocks(a);
    c.blk0 = b.blk0 + segBlocks(b);
    int total = c.blk0 + segBlocks(c);
    gseg_kernel<<<total, 256, 0, stream>>>(a, b, c, c, 3);
  };
  auto launch4 = [&](GSeg a, GSeg b, GSeg c, GSeg d) {
    a.blk0 = 0;
    b.blk0 = segBlocks(a);
    c.blk0 = b.blk0 + segBlocks(b);
    d.blk0 = c.blk0 + segBlocks(c);
    int total = d.blk0 + segBlocks(d);
    gseg_kernel<<<total, 256, 0, stream>>>(a, b, c, d, 4);
  };

  // ------------ weight prep (bf16 transposed copies)
  transp(Pd1, Pd1t, 128, 64, 0, 0, 1);
  transp(Pd2, Pd2t, 128, 32, 0, 0, 1);
  transp(Rd1, Rd1t, 128, 64, 0, 0, 1);
  transp(Rd2, Rd2t, 64, 64, 0, 0, 1);
  transp(Rd3, Rd3t, 64, 320, 0, 0, 1);
  transp(Wq0, catq,           128, 128, 128*128, 224*128, 6);
  transp(P1,  catq + 128*128, 128, 64,  128*64,  224*128, 6);
  transp(P2,  catq + 192*128, 128, 32,  128*32,  224*128, 6);
  transp(Wq1, Wq1t, 64, 64, 64*64, 64*64, 6);
  transp(Wq2, Wq2t, 32, 32, 32*32, 32*32, 6);
  transp(R1,  R1t, 128, 64, 128*64, 128*64, 6);
  transp(R2,  R2t, 64, 64, 64*64, 64*64, 6);
  transp_r3_kernel<<<(NBLK*640*64 + 255)/256, 256, 0, stream>>>(R3, R3t);
  transp(Wp0, Wp0t, 128, 128, 128*128, 128*128, 6);
  transp(Wp1, Wp1t, 64, 64, 64*64, 64*64, 6);
  transp(Wp2, Wp2t, 32, 32, 32*32, 32*32, 6);
  transp(Wi0, cati,           128, 128, 128*128, 224*128, 6);
  transp(Wg,  cati + 128*128, 128, 96,  128*96,  224*128, 6);
  transp(Wi1, Wi1t, 64, 64, 64*64, 64*64, 6);
  transp(Wi2, Wi2t, 32, 32, 32*32, 32*32, 6);
  transp(Wo0, Wo0t, 128, 128, 128*128, 128*128, 6);
  transp(Wo1, Wo1t, 64, 64, 64*64, 64*64, 6);
  transp(Wo2, Wo2t, 32, 32, 32*32, 32*32, 6);
  transp(Wf,  Wft, 128, 512, 0, 0, 1);
  transp(Wh1, Wh1t, 512, 512, 0, 0, 1);

  // ------------ precompute
  hipMemsetAsync(counts, 0, NN * 4, stream);
  hipMemsetAsync(dbins, 0, MAXD * 4, stream);
  hipMemsetAsync(d_out, 0, (size_t)out_size * 4, stream);
  gather_atom_kernel<<<(NN*128 + 255)/256, 256, 0, stream>>>(atom_z, atom_table, s_at, s_atb);
  hist_kernel<<<(NE + 255)/256, 256, 0, stream>>>(edst, counts);
  scan_kernel<<<1, 1024, 0, stream>>>(counts, indptr, nextp);
  scatter_kernel<<<(NE + 255)/256, 256, 0, stream>>>(edst, nextp, order);
  edge_perm_kernel<<<NE, 128, 0, stream>>>(pos, esrc, edst, order, srcp, rbf, y1, y2, y12);
  // degree-descending node order for attn dispatch balance
  dhist_kernel<<<(NN + 255)/256, 256, 0, stream>>>(indptr, dbins);
  dscan_kernel<<<1, MAXD, 0, stream>>>(dbins, dboff);
  dplace_kernel<<<(NN + 255)/256, 256, 0, stream>>>(indptr, dboff, norder);
  gemmF(s_atb, Pd1t, spd1, NN, 64, 128, 128, 64, 0);
  gemmF(s_atb, Pd2t, spd2, NN, 32, 128, 128, 32, 0);
  // degree radial chain (uses h2c[0] as temp; refilled by pre-pass below)
  gemmH(rbf, Rd1t, h1, NE, 64, 128, 128, 64, 1);
  gemmH(h1,  Rd2t, h2c, NE, 64, 64, 64, 64, 1);
  gemmH(h2c, Rd3t, w,  NE, 320, 64, 64, 320, 0);   // wd uses UNPERMUTED Rd3t layout
  deg_inj_kernel<<<NN, 64, 0, stream>>>(indptr, srcp, w, s_at, spd1, spd2, y1, y2, inj);
  copy_kernel<<<(NN*480 + 255)/256, 256, 0, stream>>>(inj, x, NN*480);

  // radial h2 pre-pass: x-independent, compute once for all 6 blocks
  for (int i = 0; i < 6; i++) {
    gemmH(rbf, R1t + (size_t)i*64*128, h1, NE, 64, 128, 128, 64, 1);
    gemmH(h1,  R2t + (size_t)i*64*64, h2c + (size_t)i*NE*64, NE, 64, 64, 64, 64, 1);
  }

  auto run_block = [&](int i) {
    const bf16* cq  = catq + (size_t)i * 224 * 128;
    const bf16* q1t = Wq1t + (size_t)i * 64 * 64;
    const bf16* q2t = Wq2t + (size_t)i * 32 * 32;
    const bf16* r3  = R3t  + (size_t)i * 640 * 64;
    const bf16* p0t = Wp0t + (size_t)i * 128 * 128;
    const bf16* p1t = Wp1t + (size_t)i * 64 * 64;
    const bf16* p2t = Wp2t + (size_t)i * 32 * 32;
    const bf16* ci  = cati + (size_t)i * 224 * 128;
    const bf16* i1t = Wi1t + (size_t)i * 64 * 64;
    const bf16* i2t = Wi2t + (size_t)i * 32 * 32;
    const bf16* o0t = Wo0t + (size_t)i * 128 * 128;
    const bf16* o1t = Wo1t + (size_t)i * 64 * 64;
    const bf16* o2t = Wo2t + (size_t)i * 32 * 32;

    ln_kernel<<<NN, 64, 0, stream>>>(x, xnb, xrec, xrec2);
    // Q-group (qcat|qv1|qv2) + modulate-weight GEMM, all in ONE dispatch
    launch4(mkseg(xnb,          cq,  qcat, NN,   224, 128, 128, 224, 0, 1),
            mkseg(xnb + V1_OFF, q1t, qv1,  3*NN, 64,  64,  64,  64,  0, 1),
            mkseg(xnb + V2_OFF, q2t, qv2,  5*NN, 32,  32,  32,  32,  0, 1),
            mkseg(h2c + (size_t)i*NE*64, r3, w, NE, 640, 64, 64, 640, 0, 1));
    // fused online-softmax attention (packed w + y12 + xrec; defer-max)
    attn_kernel<<<NN, 64, 0, stream>>>(norder, indptr, srcp, w, xrec, xrec2, qcat, qv1, qv2, y12, attb);
    // x += eq_linear(att, Wp) (one dispatch)
    launch3(mkseg(attb,          p0t, x,          NN,   128, 128, 128, 128, 2, 0),
            mkseg(attb + V1_OFF, p1t, x + V1_OFF, 3*NN, 64,  64,  64,  64,  2, 0),
            mkseg(attb + V2_OFF, p2t, x + V2_OFF, 5*NN, 32,  32,  32,  32,  2, 0));
    // FFN
    ln_kernel<<<NN, 64, 0, stream>>>(x, xnb, nullptr, nullptr);
    launch3(mkseg(xnb,          ci,  ycat, NN,   224, 128, 128, 224, 0, 1),
            mkseg(xnb + V1_OFF, i1t, yv1,  3*NN, 64,  64,  64,  64,  0, 1),
            mkseg(xnb + V2_OFF, i2t, yv2,  5*NN, 32,  32,  32,  32,  0, 1));
    gate_kernel<<<(NN*480 + 255)/256, 256, 0, stream>>>(ycat, ybs, yv1, yv2);
    launch3(mkseg(ybs, o0t, x,          NN,   128, 128, 128, 128, 2, 0),
            mkseg(yv1, o1t, x + V1_OFF, 3*NN, 64,  64,  64,  64,  2, 0),
            mkseg(yv2, o2t, x + V2_OFF, 5*NN, 32,  32,  32,  32,  2, 0));
  };

  // ------------ DEQ unroll: z=0; twice {x = z + inj; 5 blocks}; then block 5
  for (int t = 0; t < 2; t++) {
    if (t == 1) addinj_kernel<<<(NN*480 + 255)/256, 256, 0, stream>>>(x, inj, NN*480);
    for (int i = 0; i < 5; i++) run_block(i);
  }
  run_block(5);

  // ------------ readout (feat/hb/featb live in the dead w slot)
  cvt128_kernel<<<(NN*128 + 255)/256, 256, 0, stream>>>(x, xsb);
  gemmF(xsb, Wft, feat, NN, 512, 128, 128, 512, 0);
  ln512_kernel<<<NN, 64, 0, stream>>>(feat, featb);
  gemmF(featb, Wh1t, hb, NN, 512, 512, 512, 512, 1);
  dot_seg_kernel<<<NN, 64, 0, stream>>>(hb, Wh2, bseg, (float*)d_out);
}